// Round 15
// baseline (14199.965 us; speedup 1.0000x reference)
//
#include <hip/hip_runtime.h>
#include <hip/hip_bf16.h>

#define B_  32
#define T_  512
#define I_  512
#define H_  1024
#define O_  360
#define H3_ 3072
#define M_  (B_*T_)      // 16384

static constexpr int GRU_NB = 64;   // scan blocks (16 units each)

typedef __bf16 bf16x8 __attribute__((ext_vector_type(8)));
typedef float  f32x4  __attribute__((ext_vector_type(4)));
typedef unsigned u32x4 __attribute__((ext_vector_type(4)));

__device__ __forceinline__ float sigmoidf_(float x) {
  return 1.0f / (1.0f + __expf(-x));
}
__device__ __forceinline__ float ld_f32(const float* p) { return *p; }
__device__ __forceinline__ float ld_f32(const __hip_bfloat16* p) { return __bfloat162float(*p); }
__device__ __forceinline__ void st_f32(float* p, float v) { *p = v; }
__device__ __forceinline__ void st_f32(__hip_bfloat16* p, float v) { *p = __float2bfloat16(v); }
__device__ __forceinline__ unsigned short bf16_bits(float f) {
  __hip_bfloat16 b = __float2bfloat16(f);
  return *reinterpret_cast<unsigned short*>(&b);
}
__device__ __forceinline__ unsigned short bits_of(__hip_bfloat16 b) {
  return *reinterpret_cast<unsigned short*>(&b);
}

// ---------------------------------------------------------------- utilities
__global__ void f32_to_bf16_k(const float* __restrict__ in,
                              __hip_bfloat16* __restrict__ out, int n) {
  int i = blockIdx.x * blockDim.x + threadIdx.x;
  int stride = gridDim.x * blockDim.x;
  for (; i < n; i += stride) out[i] = __float2bfloat16(in[i]);
}

// hbuf (fp32, 2*B*H words) zeroed via agent atomic stores -> visible to the
// scan's sc1 readers. Zero = h0 = 0.0f with stamp 0 (valid init: first
// consumers want stamps 1 and 2, so no false-positive).
__global__ void gru_init_k(unsigned* __restrict__ hbuf32) {
  const int tid0  = blockIdx.x * blockDim.x + threadIdx.x;
  const int stride = gridDim.x * blockDim.x;
  for (int i = tid0; i < 2 * B_ * H_; i += stride)
    __hip_atomic_store(hbuf32 + i, 0u, __ATOMIC_RELAXED, __HIP_MEMORY_SCOPE_AGENT);
}

// ---------------------------------------------------------------- MFMA GEMM
// (unchanged from R13 — verified) split-bf16: D = Ah*Wh + Ah*Wl + Al*Wh.
template <int ACT, typename OT>
__global__ __launch_bounds__(256)
void mgemm_bt(const float* __restrict__ A, const float* __restrict__ W,
              const float* __restrict__ bias, OT* __restrict__ C,
              int M, int N, int K, int lda) {
  __shared__ __hip_bfloat16 Ah[128][40], Al[128][40];
  __shared__ __hip_bfloat16 Wh[128][40], Wl[128][40];
  const int tid  = threadIdx.x;
  const int lane = tid & 63;
  const int wv   = tid >> 6;
  const int bm   = blockIdx.y * 128;
  const int bn   = blockIdx.x * 128;
  const int msub = (wv & 1) * 64;
  const int nsub = (wv >> 1) * 64;
  const int fr   = lane & 15;
  const int fk   = lane >> 4;

  f32x4 acc[4][4];
#pragma unroll
  for (int i = 0; i < 4; ++i)
#pragma unroll
    for (int j = 0; j < 4; ++j) acc[i][j] = (f32x4){0.f, 0.f, 0.f, 0.f};

  const int sr = tid >> 1;
  const int sc = (tid & 1) * 16;
  const float* Ap = A + (size_t)(bm + sr) * lda + sc;
  const bool wok = (bn + sr) < N;
  const float* Wp = W + (size_t)(wok ? (bn + sr) : 0) * K + sc;

  for (int k0 = 0; k0 < K; k0 += 32) {
    float av[16], wvv[16];
#pragma unroll
    for (int j = 0; j < 4; ++j) {
      float4 t = *(const float4*)(Ap + k0 + j * 4);
      av[j*4+0] = t.x; av[j*4+1] = t.y; av[j*4+2] = t.z; av[j*4+3] = t.w;
      float4 u = wok ? *(const float4*)(Wp + k0 + j * 4)
                     : make_float4(0.f, 0.f, 0.f, 0.f);
      wvv[j*4+0] = u.x; wvv[j*4+1] = u.y; wvv[j*4+2] = u.z; wvv[j*4+3] = u.w;
    }

    unsigned pah[8], pal[8], pwh[8], pwl[8];
#pragma unroll
    for (int e = 0; e < 8; ++e) {
      __hip_bfloat16 a0 = __float2bfloat16(av[2*e]);
      __hip_bfloat16 a1 = __float2bfloat16(av[2*e+1]);
      pah[e] = (unsigned)bits_of(a0) | ((unsigned)bits_of(a1) << 16);
      pal[e] = (unsigned)bf16_bits(av[2*e]   - __bfloat162float(a0)) |
               ((unsigned)bf16_bits(av[2*e+1] - __bfloat162float(a1)) << 16);
      __hip_bfloat16 w0 = __float2bfloat16(wvv[2*e]);
      __hip_bfloat16 w1 = __float2bfloat16(wvv[2*e+1]);
      pwh[e] = (unsigned)bits_of(w0) | ((unsigned)bits_of(w1) << 16);
      pwl[e] = (unsigned)bf16_bits(wvv[2*e]   - __bfloat162float(w0)) |
               ((unsigned)bf16_bits(wvv[2*e+1] - __bfloat162float(w1)) << 16);
    }

    __syncthreads();
    *(uint4*)&Ah[sr][sc]     = make_uint4(pah[0], pah[1], pah[2], pah[3]);
    *(uint4*)&Ah[sr][sc + 8] = make_uint4(pah[4], pah[5], pah[6], pah[7]);
    *(uint4*)&Al[sr][sc]     = make_uint4(pal[0], pal[1], pal[2], pal[3]);
    *(uint4*)&Al[sr][sc + 8] = make_uint4(pal[4], pal[5], pal[6], pal[7]);
    *(uint4*)&Wh[sr][sc]     = make_uint4(pwh[0], pwh[1], pwh[2], pwh[3]);
    *(uint4*)&Wh[sr][sc + 8] = make_uint4(pwh[4], pwh[5], pwh[6], pwh[7]);
    *(uint4*)&Wl[sr][sc]     = make_uint4(pwl[0], pwl[1], pwl[2], pwl[3]);
    *(uint4*)&Wl[sr][sc + 8] = make_uint4(pwl[4], pwl[5], pwl[6], pwl[7]);
    __syncthreads();

    bf16x8 ah[4], al[4];
#pragma unroll
    for (int mf = 0; mf < 4; ++mf) {
      ah[mf] = *(const bf16x8*)&Ah[msub + mf * 16 + fr][fk * 8];
      al[mf] = *(const bf16x8*)&Al[msub + mf * 16 + fr][fk * 8];
    }
#pragma unroll
    for (int nf = 0; nf < 4; ++nf) {
      bf16x8 bh = *(const bf16x8*)&Wh[nsub + nf * 16 + fr][fk * 8];
      bf16x8 bl = *(const bf16x8*)&Wl[nsub + nf * 16 + fr][fk * 8];
#pragma unroll
      for (int mf = 0; mf < 4; ++mf) {
        acc[mf][nf] = __builtin_amdgcn_mfma_f32_16x16x32_bf16(ah[mf], bh, acc[mf][nf], 0, 0, 0);
        acc[mf][nf] = __builtin_amdgcn_mfma_f32_16x16x32_bf16(ah[mf], bl, acc[mf][nf], 0, 0, 0);
        acc[mf][nf] = __builtin_amdgcn_mfma_f32_16x16x32_bf16(al[mf], bh, acc[mf][nf], 0, 0, 0);
      }
    }
  }

#pragma unroll
  for (int nf = 0; nf < 4; ++nf) {
    const int n = bn + nsub + nf * 16 + fr;
    if (n < N) {
      const float bj = bias[n];
#pragma unroll
      for (int mf = 0; mf < 4; ++mf)
#pragma unroll
        for (int r = 0; r < 4; ++r) {
          const int m = bm + msub + mf * 16 + fk * 4 + r;
          float v = acc[mf][nf][r] + bj;
          if (ACT) v = fmaxf(v, 0.0f);
          st_f32(&C[(size_t)m * N + n], v);
        }
    }
  }
}

// ---------------------------------------------------------------- GRU scan
// SELF-VALIDATING DATA exchange (no tags, no RMW, no drains, no syncthreads):
// h is exchanged as fp32 with the step stamp (t+1)&3 in the 2 LSBs (below
// bf16 rounding -> A operand numerics identical to R13 up to rare 1-ulp tie
// cases). A consumer at iter t batch-loads its A rows from hbuf[t&1] (asm
// dwordx4 sc0 sc1 -- R4-proven to observe __hip_atomic_store producers) and
// accepts only when ALL 256 words carry stamp t&3; else retries.
// Lap-safety: all words of hbuf[(t+1)&1] fresh ==> every producer of this
// batch-half finished READING hbuf[t&1] (its stores depend on those loads),
// so overwriting hbuf[t&1] at iter t+1 is safe. mod-4 stamps distinguish
// t from t-2 (same buffer). Zero-init (stamp 0) cannot false-positive
// (first consumers want stamps 1 and 2); init re-zeros every launch.
// 64 blocks x 128 threads (2 waves); block owns 16 units; wave bt owns
// batch rows bt*16..+15. NOTE: xg and hs may ALIAS (fp32 path: hs
// interleaved in xg's r columns; same-lane read-then-write order).
template <typename XT>
__global__ __launch_bounds__(128)
void gru_scan(const XT* xg,                            // [B,T,3H]
              const __hip_bfloat16* __restrict__ Wbf,  // [3H][H] bf16
              const float* __restrict__ bhh,           // [3H]
              float* hs, int hs_ld,                    // [B,T,*] out
              unsigned* hbuf32) {                      // [2][B][H] fp32 (stamped)
  const int tid  = threadIdx.x;
  const int lane = tid & 63;
  const int bt   = tid >> 6;
  const int col  = lane & 15;
  const int krow = lane >> 4;
  const int u    = blockIdx.x * 16 + col;
  const int bb   = bt * 16 + krow * 4;

  const float bhr = bhh[u];
  const float bhz = bhh[H_ + u];
  const float bhn = bhh[2 * H_ + u];

  const bf16x8* Wv = (const bf16x8*)Wbf;
  const bf16x8* wr = Wv + (size_t)u * 128 + krow;
  const bf16x8* wz = wr + (size_t)H_ * 128;
  const bf16x8* wn = wz + (size_t)H_ * 128;

  f32x4 hold = {0.f, 0.f, 0.f, 0.f};

  float pxr[4], pxz[4], pxn[4];
#pragma unroll
  for (int c = 0; c < 4; ++c) {
    const XT* xp = xg + ((size_t)(bb + c) * T_ + 0) * H3_;
    pxr[c] = ld_f32(xp + u);
    pxz[c] = ld_f32(xp + H_ + u);
    pxn[c] = ld_f32(xp + 2 * H_ + u);
  }

  for (int t = 0; t < T_; ++t) {
    const int cur = t & 1;

    f32x4 ar = {0.f, 0.f, 0.f, 0.f};
    f32x4 az = {0.f, 0.f, 0.f, 0.f};
    f32x4 an = {0.f, 0.f, 0.f, 0.f};

    if (t > 0) {
      // per-lane A base: batch row (bt*16+col), k-offset krow*8 fp32
      const char* ab = (const char*)(hbuf32 + (size_t)cur * (B_ * H_) +
                                     (size_t)(bt * 16 + col) * H_ + krow * 8);
      const unsigned want = (unsigned)(t & 3);

      for (;;) {
        unsigned bad = 0;
        ar = (f32x4){0.f, 0.f, 0.f, 0.f};
        az = (f32x4){0.f, 0.f, 0.f, 0.f};
        an = (f32x4){0.f, 0.f, 0.f, 0.f};
#pragma unroll
        for (int c8 = 0; c8 < 4; ++c8) {
          u32x4 f[16];
#pragma unroll
          for (int j = 0; j < 8; ++j) {
            asm volatile("global_load_dwordx4 %0, %1, off offset:%2 sc0 sc1"
                         : "=v"(f[2*j])   : "v"(ab), "i"((c8*8 + j) * 128) : "memory");
            asm volatile("global_load_dwordx4 %0, %1, off offset:%2 sc0 sc1"
                         : "=v"(f[2*j+1]) : "v"(ab), "i"((c8*8 + j) * 128 + 16) : "memory");
          }
          asm volatile("s_waitcnt vmcnt(0)" ::: "memory");
          __builtin_amdgcn_sched_barrier(0);
#pragma unroll
          for (int j = 0; j < 8; ++j) {
            const int ks = c8 * 8 + j;
            union { unsigned short s[8]; bf16x8 v; } Ax;
#pragma unroll
            for (int e = 0; e < 4; ++e) {
              const unsigned w0 = f[2*j][e], w1 = f[2*j+1][e];
              bad |= (w0 ^ want) & 3u;
              bad |= (w1 ^ want) & 3u;
              Ax.s[e]     = bf16_bits(__uint_as_float(w0));
              Ax.s[4 + e] = bf16_bits(__uint_as_float(w1));
            }
            ar = __builtin_amdgcn_mfma_f32_16x16x32_bf16(Ax.v, wr[ks * 4], ar, 0, 0, 0);
            az = __builtin_amdgcn_mfma_f32_16x16x32_bf16(Ax.v, wz[ks * 4], az, 0, 0, 0);
            an = __builtin_amdgcn_mfma_f32_16x16x32_bf16(Ax.v, wn[ks * 4], an, 0, 0, 0);
          }
        }
        if (!__any((int)bad)) break;
        __builtin_amdgcn_s_sleep(1);
      }
      __builtin_amdgcn_sched_barrier(0);
    }
    // t == 0: A = h0 = 0 -> gh = 0 (matmul skipped exactly)

    // ---- gates + state update (fp32 master state in registers)
    float hv[4];
#pragma unroll
    for (int c = 0; c < 4; ++c) {
      const float r = sigmoidf_(pxr[c] + ar[c] + bhr);
      const float z = sigmoidf_(pxz[c] + az[c] + bhz);
      const float n = tanhf(pxn[c] + r * (an[c] + bhn));
      const float h = (1.0f - z) * n + z * hold[c];
      hold[c] = h;
      hv[c] = h;
    }

    // ---- publish stamped fp32 h_{t+1} (relaxed agent stores; no drain,
    //      no tag -- the stamp IS the readiness signal)
    unsigned* hn = hbuf32 + (size_t)(cur ^ 1) * (B_ * H_);
    const unsigned stamp = (unsigned)((t + 1) & 3);
#pragma unroll
    for (int c = 0; c < 4; ++c) {
      unsigned bits = __float_as_uint(hv[c]);
      bits = (bits & ~3u) | stamp;
      __hip_atomic_store(hn + (size_t)(bb + c) * H_ + u, bits,
                         __ATOMIC_RELAXED, __HIP_MEMORY_SCOPE_AGENT);
    }

    // ---- off-critical-path: hs stores (clean values) + xg(t+1) prefetch
#pragma unroll
    for (int c = 0; c < 4; ++c)
      hs[((size_t)(bb + c) * T_ + t) * hs_ld + u] = hv[c];

    if (t + 1 < T_) {
#pragma unroll
      for (int c = 0; c < 4; ++c) {
        const XT* xp = xg + ((size_t)(bb + c) * T_ + (t + 1)) * H3_;
        pxr[c] = ld_f32(xp + u);
        pxz[c] = ld_f32(xp + H_ + u);
        pxn[c] = ld_f32(xp + 2 * H_ + u);
      }
    }
  }
}

// ---------------------------------------------------------------- launch
extern "C" void kernel_launch(void* const* d_in, const int* in_sizes, int n_in,
                              void* d_out, int out_size, void* d_ws, size_t ws_size,
                              hipStream_t stream) {
  const float* x    = (const float*)d_in[0];
  const float* W1   = (const float*)d_in[1];
  const float* b1   = (const float*)d_in[2];
  const float* W2   = (const float*)d_in[3];
  const float* b2   = (const float*)d_in[4];
  const float* Wih  = (const float*)d_in[5];
  const float* bih  = (const float*)d_in[6];
  const float* Whh  = (const float*)d_in[7];
  const float* bhh  = (const float*)d_in[8];
  const float* Wout = (const float*)d_in[9];
  const float* bout = (const float*)d_in[10];
  float* out = (float*)d_out;

  const size_t MB = (size_t)1 << 20;
  char* ws = (char*)d_ws;

  if (ws_size >= 256 * MB) {
    // [0,64M): h2, later Wbf(6M)+hbuf(@8M, 256KB fp32)
    // [64,256M): xg fp32; h1 aliased at start; hs interleaved in r columns.
    float* h2 = (float*)ws;
    float* h1 = (float*)(ws + 64 * MB);
    float* xg = (float*)(ws + 64 * MB);
    __hip_bfloat16* Wbf = (__hip_bfloat16*)ws;
    unsigned* hbuf32 = (unsigned*)(ws + 8 * MB);
    float* hs = xg;  const int hs_ld = H3_;

    mgemm_bt<1, float><<<dim3(8, 128), 256, 0, stream>>>(x, W1, b1, h1, M_, H_, I_, I_);
    mgemm_bt<1, float><<<dim3(8, 128), 256, 0, stream>>>(h1, W2, b2, h2, M_, H_, H_, H_);
    mgemm_bt<0, float><<<dim3(24, 128), 256, 0, stream>>>(h2, Wih, bih, xg, M_, H3_, H_, H_);
    f32_to_bf16_k<<<768, 256, 0, stream>>>(Whh, Wbf, H3_ * H_);
    gru_init_k<<<32, 256, 0, stream>>>(hbuf32);
    gru_scan<float><<<GRU_NB, 128, 0, stream>>>(xg, Wbf, bhh, hs, hs_ld, hbuf32);
    mgemm_bt<0, float><<<dim3(3, 128), 256, 0, stream>>>(hs, Wout, bout, out, M_, O_, H_, hs_ld);
  } else if (ws_size >= 167 * MB) {
    float* h2 = (float*)ws;
    float* hs = (float*)ws;
    float* h1 = (float*)(ws + 64 * MB);
    __hip_bfloat16* xg  = (__hip_bfloat16*)(ws + 64 * MB);
    __hip_bfloat16* Wbf = (__hip_bfloat16*)(ws + 160 * MB);
    unsigned* hbuf32 = (unsigned*)(ws + 166 * MB);

    mgemm_bt<1, float><<<dim3(8, 128), 256, 0, stream>>>(x, W1, b1, h1, M_, H_, I_, I_);
    mgemm_bt<1, float><<<dim3(8, 128), 256, 0, stream>>>(h1, W2, b2, h2, M_, H_, H_, H_);
    mgemm_bt<0, __hip_bfloat16><<<dim3(24, 128), 256, 0, stream>>>(h2, Wih, bih, xg, M_, H3_, H_, H_);
    f32_to_bf16_k<<<768, 256, 0, stream>>>(Whh, Wbf, H3_ * H_);
    gru_init_k<<<32, 256, 0, stream>>>(hbuf32);
    gru_scan<__hip_bfloat16><<<GRU_NB, 128, 0, stream>>>(xg, Wbf, bhh, hs, H_, hbuf32);
    mgemm_bt<0, float><<<dim3(3, 128), 256, 0, stream>>>(hs, Wout, bout, out, M_, O_, H_, H_);
  }
  // else: insufficient workspace -> zeros (visible failure)
}

// Round 16
// 6744.379 us; speedup vs baseline: 2.1055x; 2.1055x over previous
//
#include <hip/hip_runtime.h>
#include <hip/hip_bf16.h>

#define B_  32
#define T_  512
#define I_  512
#define H_  1024
#define O_  360
#define H3_ 3072
#define M_  (B_*T_)      // 16384

static constexpr int GRU_NB = 64;   // scan blocks (16 units each)

typedef __bf16 bf16x8 __attribute__((ext_vector_type(8)));
typedef float  f32x4  __attribute__((ext_vector_type(4)));

__device__ __forceinline__ float sigmoidf_(float x) {
  return 1.0f / (1.0f + __expf(-x));
}
__device__ __forceinline__ float ld_f32(const float* p) { return *p; }
__device__ __forceinline__ float ld_f32(const __hip_bfloat16* p) { return __bfloat162float(*p); }
__device__ __forceinline__ void st_f32(float* p, float v) { *p = v; }
__device__ __forceinline__ void st_f32(__hip_bfloat16* p, float v) { *p = __float2bfloat16(v); }
__device__ __forceinline__ unsigned short bf16_bits(float f) {
  __hip_bfloat16 b = __float2bfloat16(f);
  return *reinterpret_cast<unsigned short*>(&b);
}
__device__ __forceinline__ unsigned short bits_of(__hip_bfloat16 b) {
  return *reinterpret_cast<unsigned short*>(&b);
}

// ---------------------------------------------------------------- utilities
__global__ void f32_to_bf16_k(const float* __restrict__ in,
                              __hip_bfloat16* __restrict__ out, int n) {
  int i = blockIdx.x * blockDim.x + threadIdx.x;
  int stride = gridDim.x * blockDim.x;
  for (; i < n; i += stride) out[i] = __float2bfloat16(in[i]);
}

// (R10 fix retained: separate loop index; tag words genuinely written.)
__global__ void gru_init_k(__hip_bfloat16* __restrict__ hbuf,
                           unsigned* __restrict__ tags) {
  const int tid0  = blockIdx.x * blockDim.x + threadIdx.x;
  const int stride = gridDim.x * blockDim.x;
  for (int i = tid0; i < 2 * B_ * H_; i += stride) hbuf[i] = __float2bfloat16(0.0f);
  if (tid0 < 256) tags[tid0] = 0u;
}

// ---------------------------------------------------------------- MFMA GEMM
// (unchanged from R13 — verified) split-bf16: D = Ah*Wh + Ah*Wl + Al*Wh,
// packed ds_write_b128 staging.
template <int ACT, typename OT>
__global__ __launch_bounds__(256)
void mgemm_bt(const float* __restrict__ A, const float* __restrict__ W,
              const float* __restrict__ bias, OT* __restrict__ C,
              int M, int N, int K, int lda) {
  __shared__ __hip_bfloat16 Ah[128][40], Al[128][40];
  __shared__ __hip_bfloat16 Wh[128][40], Wl[128][40];
  const int tid  = threadIdx.x;
  const int lane = tid & 63;
  const int wv   = tid >> 6;
  const int bm   = blockIdx.y * 128;
  const int bn   = blockIdx.x * 128;
  const int msub = (wv & 1) * 64;
  const int nsub = (wv >> 1) * 64;
  const int fr   = lane & 15;
  const int fk   = lane >> 4;

  f32x4 acc[4][4];
#pragma unroll
  for (int i = 0; i < 4; ++i)
#pragma unroll
    for (int j = 0; j < 4; ++j) acc[i][j] = (f32x4){0.f, 0.f, 0.f, 0.f};

  const int sr = tid >> 1;
  const int sc = (tid & 1) * 16;
  const float* Ap = A + (size_t)(bm + sr) * lda + sc;
  const bool wok = (bn + sr) < N;
  const float* Wp = W + (size_t)(wok ? (bn + sr) : 0) * K + sc;

  for (int k0 = 0; k0 < K; k0 += 32) {
    float av[16], wvv[16];
#pragma unroll
    for (int j = 0; j < 4; ++j) {
      float4 t = *(const float4*)(Ap + k0 + j * 4);
      av[j*4+0] = t.x; av[j*4+1] = t.y; av[j*4+2] = t.z; av[j*4+3] = t.w;
      float4 u = wok ? *(const float4*)(Wp + k0 + j * 4)
                     : make_float4(0.f, 0.f, 0.f, 0.f);
      wvv[j*4+0] = u.x; wvv[j*4+1] = u.y; wvv[j*4+2] = u.z; wvv[j*4+3] = u.w;
    }

    unsigned pah[8], pal[8], pwh[8], pwl[8];
#pragma unroll
    for (int e = 0; e < 8; ++e) {
      __hip_bfloat16 a0 = __float2bfloat16(av[2*e]);
      __hip_bfloat16 a1 = __float2bfloat16(av[2*e+1]);
      pah[e] = (unsigned)bits_of(a0) | ((unsigned)bits_of(a1) << 16);
      pal[e] = (unsigned)bf16_bits(av[2*e]   - __bfloat162float(a0)) |
               ((unsigned)bf16_bits(av[2*e+1] - __bfloat162float(a1)) << 16);
      __hip_bfloat16 w0 = __float2bfloat16(wvv[2*e]);
      __hip_bfloat16 w1 = __float2bfloat16(wvv[2*e+1]);
      pwh[e] = (unsigned)bits_of(w0) | ((unsigned)bits_of(w1) << 16);
      pwl[e] = (unsigned)bf16_bits(wvv[2*e]   - __bfloat162float(w0)) |
               ((unsigned)bf16_bits(wvv[2*e+1] - __bfloat162float(w1)) << 16);
    }

    __syncthreads();
    *(uint4*)&Ah[sr][sc]     = make_uint4(pah[0], pah[1], pah[2], pah[3]);
    *(uint4*)&Ah[sr][sc + 8] = make_uint4(pah[4], pah[5], pah[6], pah[7]);
    *(uint4*)&Al[sr][sc]     = make_uint4(pal[0], pal[1], pal[2], pal[3]);
    *(uint4*)&Al[sr][sc + 8] = make_uint4(pal[4], pal[5], pal[6], pal[7]);
    *(uint4*)&Wh[sr][sc]     = make_uint4(pwh[0], pwh[1], pwh[2], pwh[3]);
    *(uint4*)&Wh[sr][sc + 8] = make_uint4(pwh[4], pwh[5], pwh[6], pwh[7]);
    *(uint4*)&Wl[sr][sc]     = make_uint4(pwl[0], pwl[1], pwl[2], pwl[3]);
    *(uint4*)&Wl[sr][sc + 8] = make_uint4(pwl[4], pwl[5], pwl[6], pwl[7]);
    __syncthreads();

    bf16x8 ah[4], al[4];
#pragma unroll
    for (int mf = 0; mf < 4; ++mf) {
      ah[mf] = *(const bf16x8*)&Ah[msub + mf * 16 + fr][fk * 8];
      al[mf] = *(const bf16x8*)&Al[msub + mf * 16 + fr][fk * 8];
    }
#pragma unroll
    for (int nf = 0; nf < 4; ++nf) {
      bf16x8 bh = *(const bf16x8*)&Wh[nsub + nf * 16 + fr][fk * 8];
      bf16x8 bl = *(const bf16x8*)&Wl[nsub + nf * 16 + fr][fk * 8];
#pragma unroll
      for (int mf = 0; mf < 4; ++mf) {
        acc[mf][nf] = __builtin_amdgcn_mfma_f32_16x16x32_bf16(ah[mf], bh, acc[mf][nf], 0, 0, 0);
        acc[mf][nf] = __builtin_amdgcn_mfma_f32_16x16x32_bf16(ah[mf], bl, acc[mf][nf], 0, 0, 0);
        acc[mf][nf] = __builtin_amdgcn_mfma_f32_16x16x32_bf16(al[mf], bh, acc[mf][nf], 0, 0, 0);
      }
    }
  }

#pragma unroll
  for (int nf = 0; nf < 4; ++nf) {
    const int n = bn + nsub + nf * 16 + fr;
    if (n < N) {
      const float bj = bias[n];
#pragma unroll
      for (int mf = 0; mf < 4; ++mf)
#pragma unroll
        for (int r = 0; r < 4; ++r) {
          const int m = bm + msub + mf * 16 + fk * 4 + r;
          float v = acc[mf][nf][r] + bj;
          if (ACT) v = fmaxf(v, 0.0f);
          st_f32(&C[(size_t)m * N + n], v);
        }
    }
  }
}

// ---------------------------------------------------------------- GRU scan
// R13 structure (proven: tags via L3 relaxed atomics, no RMW, no
// __syncthreads in the loop) + W_hh slice (96 KB: all 3 gates x 16 units)
// staged ONCE in LDS with chunk-XOR swizzle (chunk ^ (row&7): 16-lane column
// reads spread across all 32 banks, 2-way aliasing = free). Removes 192
// KB/block/step of L2 weight traffic from the step body. An opaque zero (tz)
// is added to the per-step LDS base so LICM cannot hoist the 96 loop-
// invariant ds_reads into registers. Transport/protocol/math identical to
// R13 -> same absmax. NOTE: xg and hs may ALIAS (fp32 path).
template <typename XT>
__global__ __launch_bounds__(128)
void gru_scan(const XT* xg,                            // [B,T,3H]
              const __hip_bfloat16* __restrict__ Wbf,  // [3H][H] bf16
              const float* __restrict__ bhh,           // [3H]
              float* hs, int hs_ld,                    // [B,T,*] out
              __hip_bfloat16* hbuf,                    // [2][B][H] bf16
              unsigned* tags) {                        // [64 blocks][2 waves]
  __shared__ uint4 WL4[6144];   // 96 KiB: r,z,n gate slices, swizzled
  const int tid  = threadIdx.x;
  const int lane = tid & 63;
  const int bt   = tid >> 6;
  const int col  = lane & 15;
  const int krow = lane >> 4;
  const int u0   = blockIdx.x * 16;
  const int u    = u0 + col;
  const int bb   = bt * 16 + krow * 4;
  const int c7   = col & 7;

  // ---- one-time LDS fill: gate g, local row l, 16B chunk c; swizzled
  for (int idx = tid; idx < 6144; idx += 128) {
    const int g = idx >> 11;           // 0=r, 1=z, 2=n
    const int l = (idx >> 7) & 15;
    const int c = idx & 127;
    const uint4 src = *(const uint4*)(Wbf + ((size_t)(g * H_ + u0 + l)) * H_ + c * 8);
    WL4[g * 2048 + l * 128 + (c ^ (l & 7))] = src;
  }
  __syncthreads();

  const float bhr = bhh[u];
  const float bhz = bhh[H_ + u];
  const float bhn = bhh[2 * H_ + u];

  const unsigned* mytag = tags + ((lane << 1) | bt);
  unsigned* ourtag = tags + ((blockIdx.x << 1) | bt);

  f32x4 hold = {0.f, 0.f, 0.f, 0.f};

  float pxr[4], pxz[4], pxn[4];
#pragma unroll
  for (int c = 0; c < 4; ++c) {
    const XT* xp = xg + ((size_t)(bb + c) * T_ + 0) * H3_;
    pxr[c] = ld_f32(xp + u);
    pxz[c] = ld_f32(xp + H_ + u);
    pxn[c] = ld_f32(xp + 2 * H_ + u);
  }

  for (int t = 0; t < T_; ++t) {
    const int cur = t & 1;

    if (t > 0) {
      unsigned tg;
      do {
        tg = __hip_atomic_load(mytag, __ATOMIC_RELAXED, __HIP_MEMORY_SCOPE_AGENT);
      } while (__any(tg < (unsigned)t));
      __builtin_amdgcn_sched_barrier(0);
    }

    // opaque zero: blocks LICM from hoisting the invariant ds_reads
    int tz;
    asm volatile("v_mov_b32 %0, 0" : "=v"(tz));
    const uint4* WLp = WL4 + col * 128 + tz;

    const unsigned long long* ab =
        (const unsigned long long*)(hbuf + cur * (B_ * H_)) +
        (size_t)(bt * 16 + col) * 256 + krow * 2;

    f32x4 ar = {0.f, 0.f, 0.f, 0.f};
    f32x4 az = {0.f, 0.f, 0.f, 0.f};
    f32x4 an = {0.f, 0.f, 0.f, 0.f};
#pragma unroll 8
    for (int ks = 0; ks < 32; ++ks) {
      union { unsigned long long q[2]; bf16x8 v; } A;
      A.q[0] = __hip_atomic_load(ab + ks * 8 + 0, __ATOMIC_RELAXED, __HIP_MEMORY_SCOPE_AGENT);
      A.q[1] = __hip_atomic_load(ab + ks * 8 + 1, __ATOMIC_RELAXED, __HIP_MEMORY_SCOPE_AGENT);
      const int cx = (krow + ks * 4) ^ c7;
      bf16x8 wrv = __builtin_bit_cast(bf16x8, WLp[cx]);
      bf16x8 wzv = __builtin_bit_cast(bf16x8, WLp[2048 + cx]);
      bf16x8 wnv = __builtin_bit_cast(bf16x8, WLp[4096 + cx]);
      ar = __builtin_amdgcn_mfma_f32_16x16x32_bf16(A.v, wrv, ar, 0, 0, 0);
      az = __builtin_amdgcn_mfma_f32_16x16x32_bf16(A.v, wzv, az, 0, 0, 0);
      an = __builtin_amdgcn_mfma_f32_16x16x32_bf16(A.v, wnv, an, 0, 0, 0);
    }

    float hv[4];
#pragma unroll
    for (int c = 0; c < 4; ++c) {
      const float r = sigmoidf_(pxr[c] + ar[c] + bhr);
      const float z = sigmoidf_(pxz[c] + az[c] + bhz);
      const float n = tanhf(pxn[c] + r * (an[c] + bhn));
      const float h = (1.0f - z) * n + z * hold[c];
      hold[c] = h;
      hv[c] = h;
    }

    unsigned* hn32 = (unsigned*)(hbuf + (cur ^ 1) * (B_ * H_));
    const int ue2 = (u & ~1) >> 1;
    const int c0 = (lane & 1) ? 2 : 0;
#pragma unroll
    for (int c = 0; c < 4; ++c) {
      const float other = __shfl_xor(hv[c], 1, 64);
      unsigned p;
      if (lane & 1)
        p = (unsigned)bf16_bits(other) | ((unsigned)bf16_bits(hv[c]) << 16);
      else
        p = (unsigned)bf16_bits(hv[c]) | ((unsigned)bf16_bits(other) << 16);
      if (c == c0 || c == c0 + 1)
        __hip_atomic_store(hn32 + (size_t)(bb + c) * 512 + ue2, p,
                           __ATOMIC_RELAXED, __HIP_MEMORY_SCOPE_AGENT);
    }

    asm volatile("s_waitcnt vmcnt(0)" ::: "memory");
    if (lane == 0)
      __hip_atomic_store(ourtag, (unsigned)(t + 1),
                         __ATOMIC_RELAXED, __HIP_MEMORY_SCOPE_AGENT);

#pragma unroll
    for (int c = 0; c < 4; ++c)
      hs[((size_t)(bb + c) * T_ + t) * hs_ld + u] = hv[c];

    if (t + 1 < T_) {
#pragma unroll
      for (int c = 0; c < 4; ++c) {
        const XT* xp = xg + ((size_t)(bb + c) * T_ + (t + 1)) * H3_;
        pxr[c] = ld_f32(xp + u);
        pxz[c] = ld_f32(xp + H_ + u);
        pxn[c] = ld_f32(xp + 2 * H_ + u);
      }
    }
  }
}

// ---------------------------------------------------------------- launch
extern "C" void kernel_launch(void* const* d_in, const int* in_sizes, int n_in,
                              void* d_out, int out_size, void* d_ws, size_t ws_size,
                              hipStream_t stream) {
  const float* x    = (const float*)d_in[0];
  const float* W1   = (const float*)d_in[1];
  const float* b1   = (const float*)d_in[2];
  const float* W2   = (const float*)d_in[3];
  const float* b2   = (const float*)d_in[4];
  const float* Wih  = (const float*)d_in[5];
  const float* bih  = (const float*)d_in[6];
  const float* Whh  = (const float*)d_in[7];
  const float* bhh  = (const float*)d_in[8];
  const float* Wout = (const float*)d_in[9];
  const float* bout = (const float*)d_in[10];
  float* out = (float*)d_out;

  const size_t MB = (size_t)1 << 20;
  char* ws = (char*)d_ws;

  if (ws_size >= 256 * MB) {
    // [0,64M): h2, later Wbf(6M)+hbuf(@8M)+tags(@9M)
    // [64,256M): xg fp32; h1 aliased at start; hs interleaved in r columns.
    float* h2 = (float*)ws;
    float* h1 = (float*)(ws + 64 * MB);
    float* xg = (float*)(ws + 64 * MB);
    __hip_bfloat16* Wbf  = (__hip_bfloat16*)ws;
    __hip_bfloat16* hbuf = (__hip_bfloat16*)(ws + 8 * MB);
    unsigned* tags = (unsigned*)(ws + 9 * MB);
    float* hs = xg;  const int hs_ld = H3_;

    mgemm_bt<1, float><<<dim3(8, 128), 256, 0, stream>>>(x, W1, b1, h1, M_, H_, I_, I_);
    mgemm_bt<1, float><<<dim3(8, 128), 256, 0, stream>>>(h1, W2, b2, h2, M_, H_, H_, H_);
    mgemm_bt<0, float><<<dim3(24, 128), 256, 0, stream>>>(h2, Wih, bih, xg, M_, H3_, H_, H_);
    f32_to_bf16_k<<<768, 256, 0, stream>>>(Whh, Wbf, H3_ * H_);
    gru_init_k<<<32, 256, 0, stream>>>(hbuf, tags);
    gru_scan<float><<<GRU_NB, 128, 0, stream>>>(xg, Wbf, bhh, hs, hs_ld, hbuf, tags);
    mgemm_bt<0, float><<<dim3(3, 128), 256, 0, stream>>>(hs, Wout, bout, out, M_, O_, H_, hs_ld);
  } else if (ws_size >= 167 * MB) {
    float* h2 = (float*)ws;
    float* hs = (float*)ws;
    float* h1 = (float*)(ws + 64 * MB);
    __hip_bfloat16* xg   = (__hip_bfloat16*)(ws + 64 * MB);
    __hip_bfloat16* Wbf  = (__hip_bfloat16*)(ws + 160 * MB);
    __hip_bfloat16* hbuf = (__hip_bfloat16*)(ws + 166 * MB);
    unsigned* tags = (unsigned*)(ws + 166 * MB + 256 * 1024);

    mgemm_bt<1, float><<<dim3(8, 128), 256, 0, stream>>>(x, W1, b1, h1, M_, H_, I_, I_);
    mgemm_bt<1, float><<<dim3(8, 128), 256, 0, stream>>>(h1, W2, b2, h2, M_, H_, H_, H_);
    mgemm_bt<0, __hip_bfloat16><<<dim3(24, 128), 256, 0, stream>>>(h2, Wih, bih, xg, M_, H3_, H_, H_);
    f32_to_bf16_k<<<768, 256, 0, stream>>>(Whh, Wbf, H3_ * H_);
    gru_init_k<<<32, 256, 0, stream>>>(hbuf, tags);
    gru_scan<__hip_bfloat16><<<GRU_NB, 128, 0, stream>>>(xg, Wbf, bhh, hs, H_, hbuf, tags);
    mgemm_bt<0, float><<<dim3(3, 128), 256, 0, stream>>>(hs, Wout, bout, out, M_, O_, H_, H_);
  }
  // else: insufficient workspace -> zeros (visible failure)
}

// Round 17
// 6035.122 us; speedup vs baseline: 2.3529x; 1.1175x over previous
//
#include <hip/hip_runtime.h>
#include <hip/hip_bf16.h>

#define B_  32
#define T_  512
#define I_  512
#define H_  1024
#define O_  360
#define H3_ 3072
#define M_  (B_*T_)      // 16384

static constexpr int GRU_NB = 64;   // scan blocks (16 units each)

typedef __bf16 bf16x8 __attribute__((ext_vector_type(8)));
typedef float  f32x4  __attribute__((ext_vector_type(4)));

__device__ __forceinline__ float sigmoidf_(float x) {
  return 1.0f / (1.0f + __expf(-x));
}
__device__ __forceinline__ float ld_f32(const float* p) { return *p; }
__device__ __forceinline__ float ld_f32(const __hip_bfloat16* p) { return __bfloat162float(*p); }
__device__ __forceinline__ void st_f32(float* p, float v) { *p = v; }
__device__ __forceinline__ void st_f32(__hip_bfloat16* p, float v) { *p = __float2bfloat16(v); }
__device__ __forceinline__ unsigned short bf16_bits(float f) {
  __hip_bfloat16 b = __float2bfloat16(f);
  return *reinterpret_cast<unsigned short*>(&b);
}
__device__ __forceinline__ unsigned short bits_of(__hip_bfloat16 b) {
  return *reinterpret_cast<unsigned short*>(&b);
}

// ---------------------------------------------------------------- utilities
__global__ void f32_to_bf16_k(const float* __restrict__ in,
                              __hip_bfloat16* __restrict__ out, int n) {
  int i = blockIdx.x * blockDim.x + threadIdx.x;
  int stride = gridDim.x * blockDim.x;
  for (; i < n; i += stride) out[i] = __float2bfloat16(in[i]);
}

// Tags padded: one tag per 64B sector (16 u32). 128 tags -> 8KB zeroed.
__global__ void gru_init_k(__hip_bfloat16* __restrict__ hbuf,
                           unsigned* __restrict__ tags) {
  const int tid0  = blockIdx.x * blockDim.x + threadIdx.x;
  const int stride = gridDim.x * blockDim.x;
  for (int i = tid0; i < 2 * B_ * H_; i += stride) hbuf[i] = __float2bfloat16(0.0f);
  if (tid0 < 2048) tags[tid0] = 0u;
}

// ---------------------------------------------------------------- MFMA GEMM
// (unchanged from R13 — verified) split-bf16: D = Ah*Wh + Ah*Wl + Al*Wh,
// packed ds_write_b128 staging.
template <int ACT, typename OT>
__global__ __launch_bounds__(256)
void mgemm_bt(const float* __restrict__ A, const float* __restrict__ W,
              const float* __restrict__ bias, OT* __restrict__ C,
              int M, int N, int K, int lda) {
  __shared__ __hip_bfloat16 Ah[128][40], Al[128][40];
  __shared__ __hip_bfloat16 Wh[128][40], Wl[128][40];
  const int tid  = threadIdx.x;
  const int lane = tid & 63;
  const int wv   = tid >> 6;
  const int bm   = blockIdx.y * 128;
  const int bn   = blockIdx.x * 128;
  const int msub = (wv & 1) * 64;
  const int nsub = (wv >> 1) * 64;
  const int fr   = lane & 15;
  const int fk   = lane >> 4;

  f32x4 acc[4][4];
#pragma unroll
  for (int i = 0; i < 4; ++i)
#pragma unroll
    for (int j = 0; j < 4; ++j) acc[i][j] = (f32x4){0.f, 0.f, 0.f, 0.f};

  const int sr = tid >> 1;
  const int sc = (tid & 1) * 16;
  const float* Ap = A + (size_t)(bm + sr) * lda + sc;
  const bool wok = (bn + sr) < N;
  const float* Wp = W + (size_t)(wok ? (bn + sr) : 0) * K + sc;

  for (int k0 = 0; k0 < K; k0 += 32) {
    float av[16], wvv[16];
#pragma unroll
    for (int j = 0; j < 4; ++j) {
      float4 t = *(const float4*)(Ap + k0 + j * 4);
      av[j*4+0] = t.x; av[j*4+1] = t.y; av[j*4+2] = t.z; av[j*4+3] = t.w;
      float4 u = wok ? *(const float4*)(Wp + k0 + j * 4)
                     : make_float4(0.f, 0.f, 0.f, 0.f);
      wvv[j*4+0] = u.x; wvv[j*4+1] = u.y; wvv[j*4+2] = u.z; wvv[j*4+3] = u.w;
    }

    unsigned pah[8], pal[8], pwh[8], pwl[8];
#pragma unroll
    for (int e = 0; e < 8; ++e) {
      __hip_bfloat16 a0 = __float2bfloat16(av[2*e]);
      __hip_bfloat16 a1 = __float2bfloat16(av[2*e+1]);
      pah[e] = (unsigned)bits_of(a0) | ((unsigned)bits_of(a1) << 16);
      pal[e] = (unsigned)bf16_bits(av[2*e]   - __bfloat162float(a0)) |
               ((unsigned)bf16_bits(av[2*e+1] - __bfloat162float(a1)) << 16);
      __hip_bfloat16 w0 = __float2bfloat16(wvv[2*e]);
      __hip_bfloat16 w1 = __float2bfloat16(wvv[2*e+1]);
      pwh[e] = (unsigned)bits_of(w0) | ((unsigned)bits_of(w1) << 16);
      pwl[e] = (unsigned)bf16_bits(wvv[2*e]   - __bfloat162float(w0)) |
               ((unsigned)bf16_bits(wvv[2*e+1] - __bfloat162float(w1)) << 16);
    }

    __syncthreads();
    *(uint4*)&Ah[sr][sc]     = make_uint4(pah[0], pah[1], pah[2], pah[3]);
    *(uint4*)&Ah[sr][sc + 8] = make_uint4(pah[4], pah[5], pah[6], pah[7]);
    *(uint4*)&Al[sr][sc]     = make_uint4(pal[0], pal[1], pal[2], pal[3]);
    *(uint4*)&Al[sr][sc + 8] = make_uint4(pal[4], pal[5], pal[6], pal[7]);
    *(uint4*)&Wh[sr][sc]     = make_uint4(pwh[0], pwh[1], pwh[2], pwh[3]);
    *(uint4*)&Wh[sr][sc + 8] = make_uint4(pwh[4], pwh[5], pwh[6], pwh[7]);
    *(uint4*)&Wl[sr][sc]     = make_uint4(pwl[0], pwl[1], pwl[2], pwl[3]);
    *(uint4*)&Wl[sr][sc + 8] = make_uint4(pwl[4], pwl[5], pwl[6], pwl[7]);
    __syncthreads();

    bf16x8 ah[4], al[4];
#pragma unroll
    for (int mf = 0; mf < 4; ++mf) {
      ah[mf] = *(const bf16x8*)&Ah[msub + mf * 16 + fr][fk * 8];
      al[mf] = *(const bf16x8*)&Al[msub + mf * 16 + fr][fk * 8];
    }
#pragma unroll
    for (int nf = 0; nf < 4; ++nf) {
      bf16x8 bh = *(const bf16x8*)&Wh[nsub + nf * 16 + fr][fk * 8];
      bf16x8 bl = *(const bf16x8*)&Wl[nsub + nf * 16 + fr][fk * 8];
#pragma unroll
      for (int mf = 0; mf < 4; ++mf) {
        acc[mf][nf] = __builtin_amdgcn_mfma_f32_16x16x32_bf16(ah[mf], bh, acc[mf][nf], 0, 0, 0);
        acc[mf][nf] = __builtin_amdgcn_mfma_f32_16x16x32_bf16(ah[mf], bl, acc[mf][nf], 0, 0, 0);
        acc[mf][nf] = __builtin_amdgcn_mfma_f32_16x16x32_bf16(al[mf], bh, acc[mf][nf], 0, 0, 0);
      }
    }
  }

#pragma unroll
  for (int nf = 0; nf < 4; ++nf) {
    const int n = bn + nsub + nf * 16 + fr;
    if (n < N) {
      const float bj = bias[n];
#pragma unroll
      for (int mf = 0; mf < 4; ++mf)
#pragma unroll
        for (int r = 0; r < 4; ++r) {
          const int m = bm + msub + mf * 16 + fk * 4 + r;
          float v = acc[mf][nf][r] + bj;
          if (ACT) v = fmaxf(v, 0.0f);
          st_f32(&C[(size_t)m * N + n], v);
        }
    }
  }
}

// ---------------------------------------------------------------- GRU scan
// R16 structure (proven: LDS-resident W_hh slice, tags via L3 relaxed
// atomics, no RMW, no __syncthreads in the loop) with three latency/
// contention trims:
//  (1) tags padded to 64B sectors -> poll gather spreads over 32 L3 lines
//      instead of 4 (producer tag-store no longer queues behind the storm);
//  (2) poll backoff: immediate first check, then s_sleep(1) between
//      retries;
//  (3) unroll 16 on the K loop -> 32 A-loads per wait group (2 L3 RT
//      groups instead of 4 on the serial A path).
// Protocol & math identical to R16 -> same absmax.
// NOTE: xg and hs may ALIAS (fp32 path).
template <typename XT>
__global__ __launch_bounds__(128)
void gru_scan(const XT* xg,                            // [B,T,3H]
              const __hip_bfloat16* __restrict__ Wbf,  // [3H][H] bf16
              const float* __restrict__ bhh,           // [3H]
              float* hs, int hs_ld,                    // [B,T,*] out
              __hip_bfloat16* hbuf,                    // [2][B][H] bf16
              unsigned* tags) {                        // [128 tags x 16 u32 pad]
  __shared__ uint4 WL4[6144];   // 96 KiB: r,z,n gate slices, swizzled
  const int tid  = threadIdx.x;
  const int lane = tid & 63;
  const int bt   = tid >> 6;
  const int col  = lane & 15;
  const int krow = lane >> 4;
  const int u0   = blockIdx.x * 16;
  const int u    = u0 + col;
  const int bb   = bt * 16 + krow * 4;
  const int c7   = col & 7;

  // ---- one-time LDS fill: gate g, local row l, 16B chunk c; swizzled
  for (int idx = tid; idx < 6144; idx += 128) {
    const int g = idx >> 11;           // 0=r, 1=z, 2=n
    const int l = (idx >> 7) & 15;
    const int c = idx & 127;
    const uint4 src = *(const uint4*)(Wbf + ((size_t)(g * H_ + u0 + l)) * H_ + c * 8);
    WL4[g * 2048 + l * 128 + (c ^ (l & 7))] = src;
  }
  __syncthreads();

  const float bhr = bhh[u];
  const float bhz = bhh[H_ + u];
  const float bhn = bhh[2 * H_ + u];

  // padded tag addressing: tag (block j, wave w) at tags[(j*2 + w) * 16]
  const unsigned* mytag = tags + (((lane << 1) | bt) << 4);
  unsigned* ourtag = tags + (((blockIdx.x << 1) | bt) << 4);

  f32x4 hold = {0.f, 0.f, 0.f, 0.f};

  float pxr[4], pxz[4], pxn[4];
#pragma unroll
  for (int c = 0; c < 4; ++c) {
    const XT* xp = xg + ((size_t)(bb + c) * T_ + 0) * H3_;
    pxr[c] = ld_f32(xp + u);
    pxz[c] = ld_f32(xp + H_ + u);
    pxn[c] = ld_f32(xp + 2 * H_ + u);
  }

  for (int t = 0; t < T_; ++t) {
    const int cur = t & 1;

    if (t > 0) {
      for (;;) {
        unsigned tg = __hip_atomic_load(mytag, __ATOMIC_RELAXED,
                                        __HIP_MEMORY_SCOPE_AGENT);
        if (!__any(tg < (unsigned)t)) break;
        __builtin_amdgcn_s_sleep(1);   // backoff: ease L3 tag-bank pressure
      }
      __builtin_amdgcn_sched_barrier(0);
    }

    // opaque zero: blocks LICM from hoisting the invariant ds_reads
    int tz;
    asm volatile("v_mov_b32 %0, 0" : "=v"(tz));
    const uint4* WLp = WL4 + col * 128 + tz;

    const unsigned long long* ab =
        (const unsigned long long*)(hbuf + cur * (B_ * H_)) +
        (size_t)(bt * 16 + col) * 256 + krow * 2;

    f32x4 ar = {0.f, 0.f, 0.f, 0.f};
    f32x4 az = {0.f, 0.f, 0.f, 0.f};
    f32x4 an = {0.f, 0.f, 0.f, 0.f};
#pragma unroll 16
    for (int ks = 0; ks < 32; ++ks) {
      union { unsigned long long q[2]; bf16x8 v; } A;
      A.q[0] = __hip_atomic_load(ab + ks * 8 + 0, __ATOMIC_RELAXED, __HIP_MEMORY_SCOPE_AGENT);
      A.q[1] = __hip_atomic_load(ab + ks * 8 + 1, __ATOMIC_RELAXED, __HIP_MEMORY_SCOPE_AGENT);
      const int cx = (krow + ks * 4) ^ c7;
      bf16x8 wrv = __builtin_bit_cast(bf16x8, WLp[cx]);
      bf16x8 wzv = __builtin_bit_cast(bf16x8, WLp[2048 + cx]);
      bf16x8 wnv = __builtin_bit_cast(bf16x8, WLp[4096 + cx]);
      ar = __builtin_amdgcn_mfma_f32_16x16x32_bf16(A.v, wrv, ar, 0, 0, 0);
      az = __builtin_amdgcn_mfma_f32_16x16x32_bf16(A.v, wzv, az, 0, 0, 0);
      an = __builtin_amdgcn_mfma_f32_16x16x32_bf16(A.v, wnv, an, 0, 0, 0);
    }

    float hv[4];
#pragma unroll
    for (int c = 0; c < 4; ++c) {
      const float r = sigmoidf_(pxr[c] + ar[c] + bhr);
      const float z = sigmoidf_(pxz[c] + az[c] + bhz);
      const float n = tanhf(pxn[c] + r * (an[c] + bhn));
      const float h = (1.0f - z) * n + z * hold[c];
      hold[c] = h;
      hv[c] = h;
    }

    unsigned* hn32 = (unsigned*)(hbuf + (cur ^ 1) * (B_ * H_));
    const int ue2 = (u & ~1) >> 1;
    const int c0 = (lane & 1) ? 2 : 0;
#pragma unroll
    for (int c = 0; c < 4; ++c) {
      const float other = __shfl_xor(hv[c], 1, 64);
      unsigned p;
      if (lane & 1)
        p = (unsigned)bf16_bits(other) | ((unsigned)bf16_bits(hv[c]) << 16);
      else
        p = (unsigned)bf16_bits(hv[c]) | ((unsigned)bf16_bits(other) << 16);
      if (c == c0 || c == c0 + 1)
        __hip_atomic_store(hn32 + (size_t)(bb + c) * 512 + ue2, p,
                           __ATOMIC_RELAXED, __HIP_MEMORY_SCOPE_AGENT);
    }

    asm volatile("s_waitcnt vmcnt(0)" ::: "memory");
    if (lane == 0)
      __hip_atomic_store(ourtag, (unsigned)(t + 1),
                         __ATOMIC_RELAXED, __HIP_MEMORY_SCOPE_AGENT);

#pragma unroll
    for (int c = 0; c < 4; ++c)
      hs[((size_t)(bb + c) * T_ + t) * hs_ld + u] = hv[c];

    if (t + 1 < T_) {
#pragma unroll
      for (int c = 0; c < 4; ++c) {
        const XT* xp = xg + ((size_t)(bb + c) * T_ + (t + 1)) * H3_;
        pxr[c] = ld_f32(xp + u);
        pxz[c] = ld_f32(xp + H_ + u);
        pxn[c] = ld_f32(xp + 2 * H_ + u);
      }
    }
  }
}

// ---------------------------------------------------------------- launch
extern "C" void kernel_launch(void* const* d_in, const int* in_sizes, int n_in,
                              void* d_out, int out_size, void* d_ws, size_t ws_size,
                              hipStream_t stream) {
  const float* x    = (const float*)d_in[0];
  const float* W1   = (const float*)d_in[1];
  const float* b1   = (const float*)d_in[2];
  const float* W2   = (const float*)d_in[3];
  const float* b2   = (const float*)d_in[4];
  const float* Wih  = (const float*)d_in[5];
  const float* bih  = (const float*)d_in[6];
  const float* Whh  = (const float*)d_in[7];
  const float* bhh  = (const float*)d_in[8];
  const float* Wout = (const float*)d_in[9];
  const float* bout = (const float*)d_in[10];
  float* out = (float*)d_out;

  const size_t MB = (size_t)1 << 20;
  char* ws = (char*)d_ws;

  if (ws_size >= 256 * MB) {
    // [0,64M): h2, later Wbf(6M)+hbuf(@8M)+tags(@9M, 8KB)
    // [64,256M): xg fp32; h1 aliased at start; hs interleaved in r columns.
    float* h2 = (float*)ws;
    float* h1 = (float*)(ws + 64 * MB);
    float* xg = (float*)(ws + 64 * MB);
    __hip_bfloat16* Wbf  = (__hip_bfloat16*)ws;
    __hip_bfloat16* hbuf = (__hip_bfloat16*)(ws + 8 * MB);
    unsigned* tags = (unsigned*)(ws + 9 * MB);
    float* hs = xg;  const int hs_ld = H3_;

    mgemm_bt<1, float><<<dim3(8, 128), 256, 0, stream>>>(x, W1, b1, h1, M_, H_, I_, I_);
    mgemm_bt<1, float><<<dim3(8, 128), 256, 0, stream>>>(h1, W2, b2, h2, M_, H_, H_, H_);
    mgemm_bt<0, float><<<dim3(24, 128), 256, 0, stream>>>(h2, Wih, bih, xg, M_, H3_, H_, H_);
    f32_to_bf16_k<<<768, 256, 0, stream>>>(Whh, Wbf, H3_ * H_);
    gru_init_k<<<32, 256, 0, stream>>>(hbuf, tags);
    gru_scan<float><<<GRU_NB, 128, 0, stream>>>(xg, Wbf, bhh, hs, hs_ld, hbuf, tags);
    mgemm_bt<0, float><<<dim3(3, 128), 256, 0, stream>>>(hs, Wout, bout, out, M_, O_, H_, hs_ld);
  } else if (ws_size >= 167 * MB) {
    float* h2 = (float*)ws;
    float* hs = (float*)ws;
    float* h1 = (float*)(ws + 64 * MB);
    __hip_bfloat16* xg   = (__hip_bfloat16*)(ws + 64 * MB);
    __hip_bfloat16* Wbf  = (__hip_bfloat16*)(ws + 160 * MB);
    __hip_bfloat16* hbuf = (__hip_bfloat16*)(ws + 166 * MB);
    unsigned* tags = (unsigned*)(ws + 166 * MB + 256 * 1024);

    mgemm_bt<1, float><<<dim3(8, 128), 256, 0, stream>>>(x, W1, b1, h1, M_, H_, I_, I_);
    mgemm_bt<1, float><<<dim3(8, 128), 256, 0, stream>>>(h1, W2, b2, h2, M_, H_, H_, H_);
    mgemm_bt<0, __hip_bfloat16><<<dim3(24, 128), 256, 0, stream>>>(h2, Wih, bih, xg, M_, H3_, H_, H_);
    f32_to_bf16_k<<<768, 256, 0, stream>>>(Whh, Wbf, H3_ * H_);
    gru_init_k<<<32, 256, 0, stream>>>(hbuf, tags);
    gru_scan<__hip_bfloat16><<<GRU_NB, 128, 0, stream>>>(xg, Wbf, bhh, hs, H_, hbuf, tags);
    mgemm_bt<0, float><<<dim3(3, 128), 256, 0, stream>>>(hs, Wout, bout, out, M_, O_, H_, H_);
  }
  // else: insufficient workspace -> zeros (visible failure)
}

// Round 18
// 4526.849 us; speedup vs baseline: 3.1368x; 1.3332x over previous
//
#include <hip/hip_runtime.h>
#include <hip/hip_bf16.h>

#define B_  32
#define T_  512
#define I_  512
#define H_  1024
#define O_  360
#define H3_ 3072
#define M_  (B_*T_)      // 16384

static constexpr int GRU_NB = 64;   // scan blocks (16 units each)

typedef __bf16 bf16x8 __attribute__((ext_vector_type(8)));
typedef float  f32x4  __attribute__((ext_vector_type(4)));

__device__ __forceinline__ float sigmoidf_(float x) {
  return 1.0f / (1.0f + __expf(-x));
}
__device__ __forceinline__ float ld_f32(const float* p) { return *p; }
__device__ __forceinline__ float ld_f32(const __hip_bfloat16* p) { return __bfloat162float(*p); }
__device__ __forceinline__ void st_f32(float* p, float v) { *p = v; }
__device__ __forceinline__ void st_f32(__hip_bfloat16* p, float v) { *p = __float2bfloat16(v); }
__device__ __forceinline__ unsigned short bf16_bits(float f) {
  __hip_bfloat16 b = __float2bfloat16(f);
  return *reinterpret_cast<unsigned short*>(&b);
}
__device__ __forceinline__ unsigned short bits_of(__hip_bfloat16 b) {
  return *reinterpret_cast<unsigned short*>(&b);
}

// ---------------------------------------------------------------- utilities
__global__ void f32_to_bf16_k(const float* __restrict__ in,
                              __hip_bfloat16* __restrict__ out, int n) {
  int i = blockIdx.x * blockDim.x + threadIdx.x;
  int stride = gridDim.x * blockDim.x;
  for (; i < n; i += stride) out[i] = __float2bfloat16(in[i]);
}

// Tags padded: one tag per 64B sector (16 u32). 128 tags -> 8KB zeroed.
__global__ void gru_init_k(__hip_bfloat16* __restrict__ hbuf,
                           unsigned* __restrict__ tags) {
  const int tid0  = blockIdx.x * blockDim.x + threadIdx.x;
  const int stride = gridDim.x * blockDim.x;
  for (int i = tid0; i < 2 * B_ * H_; i += stride) hbuf[i] = __float2bfloat16(0.0f);
  if (tid0 < 2048) tags[tid0] = 0u;
}

// ---------------------------------------------------------------- MFMA GEMM
// (unchanged from R13 — verified) split-bf16: D = Ah*Wh + Ah*Wl + Al*Wh,
// packed ds_write_b128 staging.
template <int ACT, typename OT>
__global__ __launch_bounds__(256)
void mgemm_bt(const float* __restrict__ A, const float* __restrict__ W,
              const float* __restrict__ bias, OT* __restrict__ C,
              int M, int N, int K, int lda) {
  __shared__ __hip_bfloat16 Ah[128][40], Al[128][40];
  __shared__ __hip_bfloat16 Wh[128][40], Wl[128][40];
  const int tid  = threadIdx.x;
  const int lane = tid & 63;
  const int wv   = tid >> 6;
  const int bm   = blockIdx.y * 128;
  const int bn   = blockIdx.x * 128;
  const int msub = (wv & 1) * 64;
  const int nsub = (wv >> 1) * 64;
  const int fr   = lane & 15;
  const int fk   = lane >> 4;

  f32x4 acc[4][4];
#pragma unroll
  for (int i = 0; i < 4; ++i)
#pragma unroll
    for (int j = 0; j < 4; ++j) acc[i][j] = (f32x4){0.f, 0.f, 0.f, 0.f};

  const int sr = tid >> 1;
  const int sc = (tid & 1) * 16;
  const float* Ap = A + (size_t)(bm + sr) * lda + sc;
  const bool wok = (bn + sr) < N;
  const float* Wp = W + (size_t)(wok ? (bn + sr) : 0) * K + sc;

  for (int k0 = 0; k0 < K; k0 += 32) {
    float av[16], wvv[16];
#pragma unroll
    for (int j = 0; j < 4; ++j) {
      float4 t = *(const float4*)(Ap + k0 + j * 4);
      av[j*4+0] = t.x; av[j*4+1] = t.y; av[j*4+2] = t.z; av[j*4+3] = t.w;
      float4 u = wok ? *(const float4*)(Wp + k0 + j * 4)
                     : make_float4(0.f, 0.f, 0.f, 0.f);
      wvv[j*4+0] = u.x; wvv[j*4+1] = u.y; wvv[j*4+2] = u.z; wvv[j*4+3] = u.w;
    }

    unsigned pah[8], pal[8], pwh[8], pwl[8];
#pragma unroll
    for (int e = 0; e < 8; ++e) {
      __hip_bfloat16 a0 = __float2bfloat16(av[2*e]);
      __hip_bfloat16 a1 = __float2bfloat16(av[2*e+1]);
      pah[e] = (unsigned)bits_of(a0) | ((unsigned)bits_of(a1) << 16);
      pal[e] = (unsigned)bf16_bits(av[2*e]   - __bfloat162float(a0)) |
               ((unsigned)bf16_bits(av[2*e+1] - __bfloat162float(a1)) << 16);
      __hip_bfloat16 w0 = __float2bfloat16(wvv[2*e]);
      __hip_bfloat16 w1 = __float2bfloat16(wvv[2*e+1]);
      pwh[e] = (unsigned)bits_of(w0) | ((unsigned)bits_of(w1) << 16);
      pwl[e] = (unsigned)bf16_bits(wvv[2*e]   - __bfloat162float(w0)) |
               ((unsigned)bf16_bits(wvv[2*e+1] - __bfloat162float(w1)) << 16);
    }

    __syncthreads();
    *(uint4*)&Ah[sr][sc]     = make_uint4(pah[0], pah[1], pah[2], pah[3]);
    *(uint4*)&Ah[sr][sc + 8] = make_uint4(pah[4], pah[5], pah[6], pah[7]);
    *(uint4*)&Al[sr][sc]     = make_uint4(pal[0], pal[1], pal[2], pal[3]);
    *(uint4*)&Al[sr][sc + 8] = make_uint4(pal[4], pal[5], pal[6], pal[7]);
    *(uint4*)&Wh[sr][sc]     = make_uint4(pwh[0], pwh[1], pwh[2], pwh[3]);
    *(uint4*)&Wh[sr][sc + 8] = make_uint4(pwh[4], pwh[5], pwh[6], pwh[7]);
    *(uint4*)&Wl[sr][sc]     = make_uint4(pwl[0], pwl[1], pwl[2], pwl[3]);
    *(uint4*)&Wl[sr][sc + 8] = make_uint4(pwl[4], pwl[5], pwl[6], pwl[7]);
    __syncthreads();

    bf16x8 ah[4], al[4];
#pragma unroll
    for (int mf = 0; mf < 4; ++mf) {
      ah[mf] = *(const bf16x8*)&Ah[msub + mf * 16 + fr][fk * 8];
      al[mf] = *(const bf16x8*)&Al[msub + mf * 16 + fr][fk * 8];
    }
#pragma unroll
    for (int nf = 0; nf < 4; ++nf) {
      bf16x8 bh = *(const bf16x8*)&Wh[nsub + nf * 16 + fr][fk * 8];
      bf16x8 bl = *(const bf16x8*)&Wl[nsub + nf * 16 + fr][fk * 8];
#pragma unroll
      for (int mf = 0; mf < 4; ++mf) {
        acc[mf][nf] = __builtin_amdgcn_mfma_f32_16x16x32_bf16(ah[mf], bh, acc[mf][nf], 0, 0, 0);
        acc[mf][nf] = __builtin_amdgcn_mfma_f32_16x16x32_bf16(ah[mf], bl, acc[mf][nf], 0, 0, 0);
        acc[mf][nf] = __builtin_amdgcn_mfma_f32_16x16x32_bf16(al[mf], bh, acc[mf][nf], 0, 0, 0);
      }
    }
  }

#pragma unroll
  for (int nf = 0; nf < 4; ++nf) {
    const int n = bn + nsub + nf * 16 + fr;
    if (n < N) {
      const float bj = bias[n];
#pragma unroll
      for (int mf = 0; mf < 4; ++mf)
#pragma unroll
        for (int r = 0; r < 4; ++r) {
          const int m = bm + msub + mf * 16 + fk * 4 + r;
          float v = acc[mf][nf][r] + bj;
          if (ACT) v = fmaxf(v, 0.0f);
          st_f32(&C[(size_t)m * N + n], v);
        }
    }
  }
}

// ---------------------------------------------------------------- GRU scan
// R17 structure + K-SPLIT across waves: 4 waves/block (256 thr), wave
// (bt = batch half, kh = K half). Each wave issues ONE 16-chunk A-load wait
// group (the two previously-serial L3 RT groups now fly in sibling waves)
// and runs 48 MFMAs. kh=1 writes 12 partial sums to LDS (stride 13 ->
// conflict-free), one __syncthreads, kh=0 adds partials and runs the R17
// gates/publish/drain/tag path unchanged.
// Lap-safety: tag(t+1) is set by kh=0 AFTER reading partials(t) (which
// implies both kh waves completed their reads of h_t); every poll includes
// the own-block tag, so kh=1's partial write at t+1 cannot race kh=0's
// read at t. Protocol otherwise identical to R17.
// NOTE: xg and hs may ALIAS (fp32 path).
template <typename XT>
__global__ __launch_bounds__(256)
void gru_scan(const XT* xg,                            // [B,T,3H]
              const __hip_bfloat16* __restrict__ Wbf,  // [3H][H] bf16
              const float* __restrict__ bhh,           // [3H]
              float* hs, int hs_ld,                    // [B,T,*] out
              __hip_bfloat16* hbuf,                    // [2][B][H] bf16
              unsigned* tags) {                        // [128 tags x 16 u32 pad]
  __shared__ uint4 WL4[6144];      // 96 KiB: r,z,n gate slices, swizzled
  __shared__ float PS[128 * 13];   // partials (bt,lane) x 12, stride 13
  const int tid  = threadIdx.x;
  const int lane = tid & 63;
  const int wv   = tid >> 6;
  const int bt   = wv & 1;         // batch half
  const int kh   = wv >> 1;        // K half
  const int col  = lane & 15;
  const int krow = lane >> 4;
  const int u0   = blockIdx.x * 16;
  const int u    = u0 + col;
  const int bb   = bt * 16 + krow * 4;
  const int c7   = col & 7;

  // ---- one-time LDS fill: gate g, local row l, 16B chunk c; swizzled
  for (int idx = tid; idx < 6144; idx += 256) {
    const int g = idx >> 11;           // 0=r, 1=z, 2=n
    const int l = (idx >> 7) & 15;
    const int c = idx & 127;
    const uint4 src = *(const uint4*)(Wbf + ((size_t)(g * H_ + u0 + l)) * H_ + c * 8);
    WL4[g * 2048 + l * 128 + (c ^ (l & 7))] = src;
  }
  __syncthreads();

  const float bhr = bhh[u];
  const float bhz = bhh[H_ + u];
  const float bhn = bhh[2 * H_ + u];

  // padded tag addressing: tag (block j, wave w) at tags[(j*2 + w) * 16]
  const unsigned* mytag = tags + (((lane << 1) | bt) << 4);
  unsigned* ourtag = tags + (((blockIdx.x << 1) | bt) << 4);

  float* psme = PS + (bt * 64 + lane) * 13;

  f32x4 hold = {0.f, 0.f, 0.f, 0.f};

  float pxr[4], pxz[4], pxn[4];
  if (kh == 0) {
#pragma unroll
    for (int c = 0; c < 4; ++c) {
      const XT* xp = xg + ((size_t)(bb + c) * T_ + 0) * H3_;
      pxr[c] = ld_f32(xp + u);
      pxz[c] = ld_f32(xp + H_ + u);
      pxn[c] = ld_f32(xp + 2 * H_ + u);
    }
  }

  for (int t = 0; t < T_; ++t) {
    const int cur = t & 1;

    if (t > 0) {
      for (;;) {
        unsigned tg = __hip_atomic_load(mytag, __ATOMIC_RELAXED,
                                        __HIP_MEMORY_SCOPE_AGENT);
        if (!__any(tg < (unsigned)t)) break;
        __builtin_amdgcn_s_sleep(1);   // backoff: ease L3 tag-bank pressure
      }
      __builtin_amdgcn_sched_barrier(0);
    }

    // opaque zero: blocks LICM from hoisting the invariant ds_reads
    int tz;
    asm volatile("v_mov_b32 %0, 0" : "=v"(tz));
    const uint4* WLp = WL4 + col * 128 + tz;

    // this wave's K-half: 16 chunks, single wait group
    const unsigned long long* ab =
        (const unsigned long long*)(hbuf + cur * (B_ * H_)) +
        (size_t)(bt * 16 + col) * 256 + kh * 128 + krow * 2;

    f32x4 ar = {0.f, 0.f, 0.f, 0.f};
    f32x4 az = {0.f, 0.f, 0.f, 0.f};
    f32x4 an = {0.f, 0.f, 0.f, 0.f};
#pragma unroll 16
    for (int ks = 0; ks < 16; ++ks) {
      union { unsigned long long q[2]; bf16x8 v; } A;
      A.q[0] = __hip_atomic_load(ab + ks * 8 + 0, __ATOMIC_RELAXED, __HIP_MEMORY_SCOPE_AGENT);
      A.q[1] = __hip_atomic_load(ab + ks * 8 + 1, __ATOMIC_RELAXED, __HIP_MEMORY_SCOPE_AGENT);
      const int cx = (krow + (kh * 16 + ks) * 4) ^ c7;
      bf16x8 wrv = __builtin_bit_cast(bf16x8, WLp[cx]);
      bf16x8 wzv = __builtin_bit_cast(bf16x8, WLp[2048 + cx]);
      bf16x8 wnv = __builtin_bit_cast(bf16x8, WLp[4096 + cx]);
      ar = __builtin_amdgcn_mfma_f32_16x16x32_bf16(A.v, wrv, ar, 0, 0, 0);
      az = __builtin_amdgcn_mfma_f32_16x16x32_bf16(A.v, wzv, az, 0, 0, 0);
      an = __builtin_amdgcn_mfma_f32_16x16x32_bf16(A.v, wnv, an, 0, 0, 0);
    }

    if (kh == 1) {
#pragma unroll
      for (int c = 0; c < 4; ++c) {
        psme[c]     = ar[c];
        psme[4 + c] = az[c];
        psme[8 + c] = an[c];
      }
    }
    __syncthreads();

    if (kh == 0) {
#pragma unroll
      for (int c = 0; c < 4; ++c) {
        ar[c] += psme[c];
        az[c] += psme[4 + c];
        an[c] += psme[8 + c];
      }

      float hv[4];
#pragma unroll
      for (int c = 0; c < 4; ++c) {
        const float r = sigmoidf_(pxr[c] + ar[c] + bhr);
        const float z = sigmoidf_(pxz[c] + az[c] + bhz);
        const float n = tanhf(pxn[c] + r * (an[c] + bhn));
        const float h = (1.0f - z) * n + z * hold[c];
        hold[c] = h;
        hv[c] = h;
      }

      unsigned* hn32 = (unsigned*)(hbuf + (cur ^ 1) * (B_ * H_));
      const int ue2 = (u & ~1) >> 1;
      const int c0 = (lane & 1) ? 2 : 0;
#pragma unroll
      for (int c = 0; c < 4; ++c) {
        const float other = __shfl_xor(hv[c], 1, 64);
        unsigned p;
        if (lane & 1)
          p = (unsigned)bf16_bits(other) | ((unsigned)bf16_bits(hv[c]) << 16);
        else
          p = (unsigned)bf16_bits(hv[c]) | ((unsigned)bf16_bits(other) << 16);
        if (c == c0 || c == c0 + 1)
          __hip_atomic_store(hn32 + (size_t)(bb + c) * 512 + ue2, p,
                             __ATOMIC_RELAXED, __HIP_MEMORY_SCOPE_AGENT);
      }

      asm volatile("s_waitcnt vmcnt(0)" ::: "memory");
      if (lane == 0)
        __hip_atomic_store(ourtag, (unsigned)(t + 1),
                           __ATOMIC_RELAXED, __HIP_MEMORY_SCOPE_AGENT);

#pragma unroll
      for (int c = 0; c < 4; ++c)
        hs[((size_t)(bb + c) * T_ + t) * hs_ld + u] = hv[c];

      if (t + 1 < T_) {
#pragma unroll
        for (int c = 0; c < 4; ++c) {
          const XT* xp = xg + ((size_t)(bb + c) * T_ + (t + 1)) * H3_;
          pxr[c] = ld_f32(xp + u);
          pxz[c] = ld_f32(xp + H_ + u);
          pxn[c] = ld_f32(xp + 2 * H_ + u);
        }
      }
    }
  }
}

// ---------------------------------------------------------------- launch
extern "C" void kernel_launch(void* const* d_in, const int* in_sizes, int n_in,
                              void* d_out, int out_size, void* d_ws, size_t ws_size,
                              hipStream_t stream) {
  const float* x    = (const float*)d_in[0];
  const float* W1   = (const float*)d_in[1];
  const float* b1   = (const float*)d_in[2];
  const float* W2   = (const float*)d_in[3];
  const float* b2   = (const float*)d_in[4];
  const float* Wih  = (const float*)d_in[5];
  const float* bih  = (const float*)d_in[6];
  const float* Whh  = (const float*)d_in[7];
  const float* bhh  = (const float*)d_in[8];
  const float* Wout = (const float*)d_in[9];
  const float* bout = (const float*)d_in[10];
  float* out = (float*)d_out;

  const size_t MB = (size_t)1 << 20;
  char* ws = (char*)d_ws;

  if (ws_size >= 256 * MB) {
    // [0,64M): h2, later Wbf(6M)+hbuf(@8M)+tags(@9M, 8KB)
    // [64,256M): xg fp32; h1 aliased at start; hs interleaved in r columns.
    float* h2 = (float*)ws;
    float* h1 = (float*)(ws + 64 * MB);
    float* xg = (float*)(ws + 64 * MB);
    __hip_bfloat16* Wbf  = (__hip_bfloat16*)ws;
    __hip_bfloat16* hbuf = (__hip_bfloat16*)(ws + 8 * MB);
    unsigned* tags = (unsigned*)(ws + 9 * MB);
    float* hs = xg;  const int hs_ld = H3_;

    mgemm_bt<1, float><<<dim3(8, 128), 256, 0, stream>>>(x, W1, b1, h1, M_, H_, I_, I_);
    mgemm_bt<1, float><<<dim3(8, 128), 256, 0, stream>>>(h1, W2, b2, h2, M_, H_, H_, H_);
    mgemm_bt<0, float><<<dim3(24, 128), 256, 0, stream>>>(h2, Wih, bih, xg, M_, H3_, H_, H_);
    f32_to_bf16_k<<<768, 256, 0, stream>>>(Whh, Wbf, H3_ * H_);
    gru_init_k<<<32, 256, 0, stream>>>(hbuf, tags);
    gru_scan<float><<<GRU_NB, 256, 0, stream>>>(xg, Wbf, bhh, hs, hs_ld, hbuf, tags);
    mgemm_bt<0, float><<<dim3(3, 128), 256, 0, stream>>>(hs, Wout, bout, out, M_, O_, H_, hs_ld);
  } else if (ws_size >= 167 * MB) {
    float* h2 = (float*)ws;
    float* hs = (float*)ws;
    float* h1 = (float*)(ws + 64 * MB);
    __hip_bfloat16* xg   = (__hip_bfloat16*)(ws + 64 * MB);
    __hip_bfloat16* Wbf  = (__hip_bfloat16*)(ws + 160 * MB);
    __hip_bfloat16* hbuf = (__hip_bfloat16*)(ws + 166 * MB);
    unsigned* tags = (unsigned*)(ws + 166 * MB + 256 * 1024);

    mgemm_bt<1, float><<<dim3(8, 128), 256, 0, stream>>>(x, W1, b1, h1, M_, H_, I_, I_);
    mgemm_bt<1, float><<<dim3(8, 128), 256, 0, stream>>>(h1, W2, b2, h2, M_, H_, H_, H_);
    mgemm_bt<0, __hip_bfloat16><<<dim3(24, 128), 256, 0, stream>>>(h2, Wih, bih, xg, M_, H3_, H_, H_);
    f32_to_bf16_k<<<768, 256, 0, stream>>>(Whh, Wbf, H3_ * H_);
    gru_init_k<<<32, 256, 0, stream>>>(hbuf, tags);
    gru_scan<__hip_bfloat16><<<GRU_NB, 256, 0, stream>>>(xg, Wbf, bhh, hs, H_, hbuf, tags);
    mgemm_bt<0, float><<<dim3(3, 128), 256, 0, stream>>>(hs, Wout, bout, out, M_, O_, H_, H_);
  }
  // else: insufficient workspace -> zeros (visible failure)
}

// Round 20
// 3771.275 us; speedup vs baseline: 3.7653x; 1.2003x over previous
//
#include <hip/hip_runtime.h>
#include <hip/hip_bf16.h>

#define B_  32
#define T_  512
#define I_  512
#define H_  1024
#define O_  360
#define H3_ 3072
#define M_  (B_*T_)      // 16384

static constexpr int GRU_NB = 64;   // scan blocks (16 units each)

typedef __bf16 bf16x8 __attribute__((ext_vector_type(8)));
typedef float  f32x4  __attribute__((ext_vector_type(4)));

__device__ __forceinline__ float sigmoidf_(float x) {
  return 1.0f / (1.0f + __expf(-x));
}
// fast tanh via expf: exact at saturation, ~1e-7 rel err midrange
__device__ __forceinline__ float tanhf_(float x) {
  float e = __expf(2.0f * x);
  return 1.0f - 2.0f / (e + 1.0f);
}
__device__ __forceinline__ float ld_f32(const float* p) { return *p; }
__device__ __forceinline__ float ld_f32(const __hip_bfloat16* p) { return __bfloat162float(*p); }
__device__ __forceinline__ void st_f32(float* p, float v) { *p = v; }
__device__ __forceinline__ void st_f32(__hip_bfloat16* p, float v) { *p = __float2bfloat16(v); }
__device__ __forceinline__ unsigned short bf16_bits(float f) {
  __hip_bfloat16 b = __float2bfloat16(f);
  return *reinterpret_cast<unsigned short*>(&b);
}
__device__ __forceinline__ unsigned short bits_of(__hip_bfloat16 b) {
  return *reinterpret_cast<unsigned short*>(&b);
}

// ---------------------------------------------------------------- utilities
__global__ void f32_to_bf16_k(const float* __restrict__ in,
                              __hip_bfloat16* __restrict__ out, int n) {
  int i = blockIdx.x * blockDim.x + threadIdx.x;
  int stride = gridDim.x * blockDim.x;
  for (; i < n; i += stride) out[i] = __float2bfloat16(in[i]);
}

// 256 tags (block x bt x kh), one per 64B sector -> 16KB zeroed.
__global__ void gru_init_k(__hip_bfloat16* __restrict__ hbuf,
                           unsigned* __restrict__ tags) {
  const int tid0  = blockIdx.x * blockDim.x + threadIdx.x;
  const int stride = gridDim.x * blockDim.x;
  for (int i = tid0; i < 2 * B_ * H_; i += stride) hbuf[i] = __float2bfloat16(0.0f);
  if (tid0 < 4096) tags[tid0] = 0u;
}

// ---------------------------------------------------------------- MFMA GEMM
// (unchanged from R13 — verified) split-bf16: D = Ah*Wh + Ah*Wl + Al*Wh,
// packed ds_write_b128 staging.
template <int ACT, typename OT>
__global__ __launch_bounds__(256)
void mgemm_bt(const float* __restrict__ A, const float* __restrict__ W,
              const float* __restrict__ bias, OT* __restrict__ C,
              int M, int N, int K, int lda) {
  __shared__ __hip_bfloat16 Ah[128][40], Al[128][40];
  __shared__ __hip_bfloat16 Wh[128][40], Wl[128][40];
  const int tid  = threadIdx.x;
  const int lane = tid & 63;
  const int wv   = tid >> 6;
  const int bm   = blockIdx.y * 128;
  const int bn   = blockIdx.x * 128;
  const int msub = (wv & 1) * 64;
  const int nsub = (wv >> 1) * 64;
  const int fr   = lane & 15;
  const int fk   = lane >> 4;

  f32x4 acc[4][4];
#pragma unroll
  for (int i = 0; i < 4; ++i)
#pragma unroll
    for (int j = 0; j < 4; ++j) acc[i][j] = (f32x4){0.f, 0.f, 0.f, 0.f};

  const int sr = tid >> 1;
  const int sc = (tid & 1) * 16;
  const float* Ap = A + (size_t)(bm + sr) * lda + sc;
  const bool wok = (bn + sr) < N;
  const float* Wp = W + (size_t)(wok ? (bn + sr) : 0) * K + sc;

  for (int k0 = 0; k0 < K; k0 += 32) {
    float av[16], wvv[16];
#pragma unroll
    for (int j = 0; j < 4; ++j) {
      float4 t = *(const float4*)(Ap + k0 + j * 4);
      av[j*4+0] = t.x; av[j*4+1] = t.y; av[j*4+2] = t.z; av[j*4+3] = t.w;
      float4 u = wok ? *(const float4*)(Wp + k0 + j * 4)
                     : make_float4(0.f, 0.f, 0.f, 0.f);
      wvv[j*4+0] = u.x; wvv[j*4+1] = u.y; wvv[j*4+2] = u.z; wvv[j*4+3] = u.w;
    }

    unsigned pah[8], pal[8], pwh[8], pwl[8];
#pragma unroll
    for (int e = 0; e < 8; ++e) {
      __hip_bfloat16 a0 = __float2bfloat16(av[2*e]);
      __hip_bfloat16 a1 = __float2bfloat16(av[2*e+1]);
      pah[e] = (unsigned)bits_of(a0) | ((unsigned)bits_of(a1) << 16);
      pal[e] = (unsigned)bf16_bits(av[2*e]   - __bfloat162float(a0)) |
               ((unsigned)bf16_bits(av[2*e+1] - __bfloat162float(a1)) << 16);
      __hip_bfloat16 w0 = __float2bfloat16(wvv[2*e]);
      __hip_bfloat16 w1 = __float2bfloat16(wvv[2*e+1]);
      pwh[e] = (unsigned)bits_of(w0) | ((unsigned)bits_of(w1) << 16);
      pwl[e] = (unsigned)bf16_bits(wvv[2*e]   - __bfloat162float(w0)) |
               ((unsigned)bf16_bits(wvv[2*e+1] - __bfloat162float(w1)) << 16);
    }

    __syncthreads();
    *(uint4*)&Ah[sr][sc]     = make_uint4(pah[0], pah[1], pah[2], pah[3]);
    *(uint4*)&Ah[sr][sc + 8] = make_uint4(pah[4], pah[5], pah[6], pah[7]);
    *(uint4*)&Al[sr][sc]     = make_uint4(pal[0], pal[1], pal[2], pal[3]);
    *(uint4*)&Al[sr][sc + 8] = make_uint4(pal[4], pal[5], pal[6], pal[7]);
    *(uint4*)&Wh[sr][sc]     = make_uint4(pwh[0], pwh[1], pwh[2], pwh[3]);
    *(uint4*)&Wh[sr][sc + 8] = make_uint4(pwh[4], pwh[5], pwh[6], pwh[7]);
    *(uint4*)&Wl[sr][sc]     = make_uint4(pwl[0], pwl[1], pwl[2], pwl[3]);
    *(uint4*)&Wl[sr][sc + 8] = make_uint4(pwl[4], pwl[5], pwl[6], pwl[7]);
    __syncthreads();

    bf16x8 ah[4], al[4];
#pragma unroll
    for (int mf = 0; mf < 4; ++mf) {
      ah[mf] = *(const bf16x8*)&Ah[msub + mf * 16 + fr][fk * 8];
      al[mf] = *(const bf16x8*)&Al[msub + mf * 16 + fr][fk * 8];
    }
#pragma unroll
    for (int nf = 0; nf < 4; ++nf) {
      bf16x8 bh = *(const bf16x8*)&Wh[nsub + nf * 16 + fr][fk * 8];
      bf16x8 bl = *(const bf16x8*)&Wl[nsub + nf * 16 + fr][fk * 8];
#pragma unroll
      for (int mf = 0; mf < 4; ++mf) {
        acc[mf][nf] = __builtin_amdgcn_mfma_f32_16x16x32_bf16(ah[mf], bh, acc[mf][nf], 0, 0, 0);
        acc[mf][nf] = __builtin_amdgcn_mfma_f32_16x16x32_bf16(ah[mf], bl, acc[mf][nf], 0, 0, 0);
        acc[mf][nf] = __builtin_amdgcn_mfma_f32_16x16x32_bf16(al[mf], bh, acc[mf][nf], 0, 0, 0);
      }
    }
  }

#pragma unroll
  for (int nf = 0; nf < 4; ++nf) {
    const int n = bn + nsub + nf * 16 + fr;
    if (n < N) {
      const float bj = bias[n];
#pragma unroll
      for (int mf = 0; mf < 4; ++mf)
#pragma unroll
        for (int r = 0; r < 4; ++r) {
          const int m = bm + msub + mf * 16 + fk * 4 + r;
          float v = acc[mf][nf][r] + bj;
          if (ACT) v = fmaxf(v, 0.0f);
          st_f32(&C[(size_t)m * N + n], v);
        }
    }
  }
}

// ---------------------------------------------------------------- GRU scan
// R18 structure (K-split: 4 waves = (bt, kh); LDS-resident W_hh; padded L3
// tags, no RMW) + GATE-SPLIT + fast tanh. The R19 pipelined-asm poll is
// REVERTED (missing early-clobber corrupted the address regs -> fault);
// poll is the R18-proven __hip_atomic_load + s_sleep backoff, now reading
// BOTH kh tags per block (compiler-managed waits).
// Gate-split: wave kh computes gates/publish/drain for batch rows
// c = 2kh..2kh+1 (partials cross-exchanged via the existing LDS barrier)
// and raises its OWN (block,bt,kh) tag -> gates latency halves, drains
// parallel, no extra barrier.
// Lap-safety: tag(block,bt,kh)=t implies that wave's A-reads of h(t-1) and
// its PS reads completed (reads < publish < drain < tag); consumers poll
// ALL same-bt tags (both kh of all 64 blocks), so buffer and PS reuse stay
// ordered. NOTE: xg and hs may ALIAS (fp32 path).
template <typename XT>
__global__ __launch_bounds__(256)
void gru_scan(const XT* xg,                            // [B,T,3H]
              const __hip_bfloat16* __restrict__ Wbf,  // [3H][H] bf16
              const float* __restrict__ bhh,           // [3H]
              float* hs, int hs_ld,                    // [B,T,*] out
              __hip_bfloat16* hbuf,                    // [2][B][H] bf16
              unsigned* tags) {                        // [256 tags x 16 u32 pad]
  __shared__ uint4 WL4[6144];      // 96 KiB: r,z,n gate slices, swizzled
  __shared__ float PS[128 * 13];   // partial exchange, stride 13
  const int tid  = threadIdx.x;
  const int lane = tid & 63;
  const int wv   = tid >> 6;
  const int bt   = wv & 1;         // batch half
  const int kh   = wv >> 1;        // K half (also owns c-rows 2kh..2kh+1)
  const int col  = lane & 15;
  const int krow = lane >> 4;
  const int u0   = blockIdx.x * 16;
  const int u    = u0 + col;
  const int bb   = bt * 16 + krow * 4;
  const int c7   = col & 7;
  const int cb   = kh * 2;         // this wave's first owned c-row

  // ---- one-time LDS fill: gate g, local row l, 16B chunk c; swizzled
  for (int idx = tid; idx < 6144; idx += 256) {
    const int g = idx >> 11;           // 0=r, 1=z, 2=n
    const int l = (idx >> 7) & 15;
    const int c = idx & 127;
    const uint4 src = *(const uint4*)(Wbf + ((size_t)(g * H_ + u0 + l)) * H_ + c * 8);
    WL4[g * 2048 + l * 128 + (c ^ (l & 7))] = src;
  }
  __syncthreads();

  const float bhr = bhh[u];
  const float bhz = bhh[H_ + u];
  const float bhn = bhh[2 * H_ + u];

  // tag layout: index ((block<<2)|(bt<<1)|kh) * 16
  const unsigned* tp0 = tags + ((((lane << 1) | bt) << 1) << 4);  // kh=0 of block `lane`
  unsigned* ourtag = tags + ((((blockIdx.x << 1) | bt) << 1 | kh) << 4);

  float* psme = PS + (bt * 64 + lane) * 13;

  float hold[2] = {0.f, 0.f};

  float pxr[2], pxz[2], pxn[2];
#pragma unroll
  for (int c = 0; c < 2; ++c) {
    const XT* xp = xg + ((size_t)(bb + cb + c) * T_ + 0) * H3_;
    pxr[c] = ld_f32(xp + u);
    pxz[c] = ld_f32(xp + H_ + u);
    pxn[c] = ld_f32(xp + 2 * H_ + u);
  }

  for (int t = 0; t < T_; ++t) {
    const int cur = t & 1;

    // ---- wait: both kh tags of every same-bt wave reached t
    if (t > 0) {
      const unsigned want = (unsigned)t;
      for (;;) {
        const unsigned g0 = __hip_atomic_load(tp0, __ATOMIC_RELAXED,
                                              __HIP_MEMORY_SCOPE_AGENT);
        const unsigned g1 = __hip_atomic_load(tp0 + 16, __ATOMIC_RELAXED,
                                              __HIP_MEMORY_SCOPE_AGENT);
        if (!__any((g0 < want) || (g1 < want))) break;
        __builtin_amdgcn_s_sleep(1);   // backoff: ease L3 tag-bank pressure
      }
      __builtin_amdgcn_sched_barrier(0);
    }

    // opaque zero: blocks LICM from hoisting the invariant ds_reads
    int tz;
    asm volatile("v_mov_b32 %0, 0" : "=v"(tz));
    const uint4* WLp = WL4 + col * 128 + tz;

    // this wave's K-half: 16 chunks, single wait group
    const unsigned long long* ab =
        (const unsigned long long*)(hbuf + cur * (B_ * H_)) +
        (size_t)(bt * 16 + col) * 256 + kh * 128 + krow * 2;

    f32x4 ar = {0.f, 0.f, 0.f, 0.f};
    f32x4 az = {0.f, 0.f, 0.f, 0.f};
    f32x4 an = {0.f, 0.f, 0.f, 0.f};
#pragma unroll 16
    for (int ks = 0; ks < 16; ++ks) {
      union { unsigned long long q[2]; bf16x8 v; } A;
      A.q[0] = __hip_atomic_load(ab + ks * 8 + 0, __ATOMIC_RELAXED, __HIP_MEMORY_SCOPE_AGENT);
      A.q[1] = __hip_atomic_load(ab + ks * 8 + 1, __ATOMIC_RELAXED, __HIP_MEMORY_SCOPE_AGENT);
      const int cx = (krow + (kh * 16 + ks) * 4) ^ c7;
      bf16x8 wrv = __builtin_bit_cast(bf16x8, WLp[cx]);
      bf16x8 wzv = __builtin_bit_cast(bf16x8, WLp[2048 + cx]);
      bf16x8 wnv = __builtin_bit_cast(bf16x8, WLp[4096 + cx]);
      ar = __builtin_amdgcn_mfma_f32_16x16x32_bf16(A.v, wrv, ar, 0, 0, 0);
      az = __builtin_amdgcn_mfma_f32_16x16x32_bf16(A.v, wzv, az, 0, 0, 0);
      an = __builtin_amdgcn_mfma_f32_16x16x32_bf16(A.v, wnv, an, 0, 0, 0);
    }

    // ---- cross-exchange the partials for the OTHER wave's c-rows
    // kh=0 writes its c=2,3 at [0..5]; kh=1 writes its c=0,1 at [6..11]
    {
      const int co = 2 - cb;            // other wave's first c-row
      const int wbase = kh ? 6 : 0;
      psme[wbase + 0] = ar[co];     psme[wbase + 1] = az[co];
      psme[wbase + 2] = an[co];     psme[wbase + 3] = ar[co + 1];
      psme[wbase + 4] = az[co + 1]; psme[wbase + 5] = an[co + 1];
    }
    __syncthreads();

    // ---- reduce own c-rows, gates, publish, drain, own tag
    const int rbase = kh ? 0 : 6;
    float hv[2];
#pragma unroll
    for (int c = 0; c < 2; ++c) {
      const float sr_ = ar[cb + c] + psme[rbase + c * 3 + 0];
      const float sz_ = az[cb + c] + psme[rbase + c * 3 + 1];
      const float sn_ = an[cb + c] + psme[rbase + c * 3 + 2];
      const float r = sigmoidf_(pxr[c] + sr_ + bhr);
      const float z = sigmoidf_(pxz[c] + sz_ + bhz);
      const float n = tanhf_(pxn[c] + r * (sn_ + bhn));
      const float h = (1.0f - z) * n + z * hold[c];
      hold[c] = h;
      hv[c] = h;
    }

    // publish: even-col lanes store the (u,u+1) packed word for each row
    unsigned* hn32 = (unsigned*)(hbuf + (cur ^ 1) * (B_ * H_));
    const int ue2 = (u & ~1) >> 1;
#pragma unroll
    for (int c = 0; c < 2; ++c) {
      const float other = __shfl_xor(hv[c], 1, 64);
      if (!(lane & 1)) {
        const unsigned p = (unsigned)bf16_bits(hv[c]) |
                           ((unsigned)bf16_bits(other) << 16);
        __hip_atomic_store(hn32 + (size_t)(bb + cb + c) * 512 + ue2, p,
                           __ATOMIC_RELAXED, __HIP_MEMORY_SCOPE_AGENT);
      }
    }

    asm volatile("s_waitcnt vmcnt(0)" ::: "memory");
    if (lane == 0)
      __hip_atomic_store(ourtag, (unsigned)(t + 1),
                         __ATOMIC_RELAXED, __HIP_MEMORY_SCOPE_AGENT);

    // ---- off-critical-path: hs stores + xg(t+1) prefetch (own 2 rows)
#pragma unroll
    for (int c = 0; c < 2; ++c)
      hs[((size_t)(bb + cb + c) * T_ + t) * hs_ld + u] = hv[c];

    if (t + 1 < T_) {
#pragma unroll
      for (int c = 0; c < 2; ++c) {
        const XT* xp = xg + ((size_t)(bb + cb + c) * T_ + (t + 1)) * H3_;
        pxr[c] = ld_f32(xp + u);
        pxz[c] = ld_f32(xp + H_ + u);
        pxn[c] = ld_f32(xp + 2 * H_ + u);
      }
    }
  }
}

// ---------------------------------------------------------------- launch
extern "C" void kernel_launch(void* const* d_in, const int* in_sizes, int n_in,
                              void* d_out, int out_size, void* d_ws, size_t ws_size,
                              hipStream_t stream) {
  const float* x    = (const float*)d_in[0];
  const float* W1   = (const float*)d_in[1];
  const float* b1   = (const float*)d_in[2];
  const float* W2   = (const float*)d_in[3];
  const float* b2   = (const float*)d_in[4];
  const float* Wih  = (const float*)d_in[5];
  const float* bih  = (const float*)d_in[6];
  const float* Whh  = (const float*)d_in[7];
  const float* bhh  = (const float*)d_in[8];
  const float* Wout = (const float*)d_in[9];
  const float* bout = (const float*)d_in[10];
  float* out = (float*)d_out;

  const size_t MB = (size_t)1 << 20;
  char* ws = (char*)d_ws;

  if (ws_size >= 256 * MB) {
    // [0,64M): h2, later Wbf(6M)+hbuf(@8M)+tags(@9M, 16KB)
    // [64,256M): xg fp32; h1 aliased at start; hs interleaved in r columns.
    float* h2 = (float*)ws;
    float* h1 = (float*)(ws + 64 * MB);
    float* xg = (float*)(ws + 64 * MB);
    __hip_bfloat16* Wbf  = (__hip_bfloat16*)ws;
    __hip_bfloat16* hbuf = (__hip_bfloat16*)(ws + 8 * MB);
    unsigned* tags = (unsigned*)(ws + 9 * MB);
    float* hs = xg;  const int hs_ld = H3_;

    mgemm_bt<1, float><<<dim3(8, 128), 256, 0, stream>>>(x, W1, b1, h1, M_, H_, I_, I_);
    mgemm_bt<1, float><<<dim3(8, 128), 256, 0, stream>>>(h1, W2, b2, h2, M_, H_, H_, H_);
    mgemm_bt<0, float><<<dim3(24, 128), 256, 0, stream>>>(h2, Wih, bih, xg, M_, H3_, H_, H_);
    f32_to_bf16_k<<<768, 256, 0, stream>>>(Whh, Wbf, H3_ * H_);
    gru_init_k<<<32, 256, 0, stream>>>(hbuf, tags);
    gru_scan<float><<<GRU_NB, 256, 0, stream>>>(xg, Wbf, bhh, hs, hs_ld, hbuf, tags);
    mgemm_bt<0, float><<<dim3(3, 128), 256, 0, stream>>>(hs, Wout, bout, out, M_, O_, H_, hs_ld);
  } else if (ws_size >= 167 * MB) {
    float* h2 = (float*)ws;
    float* hs = (float*)ws;
    float* h1 = (float*)(ws + 64 * MB);
    __hip_bfloat16* xg   = (__hip_bfloat16*)(ws + 64 * MB);
    __hip_bfloat16* Wbf  = (__hip_bfloat16*)(ws + 160 * MB);
    __hip_bfloat16* hbuf = (__hip_bfloat16*)(ws + 166 * MB);
    unsigned* tags = (unsigned*)(ws + 166 * MB + 256 * 1024);

    mgemm_bt<1, float><<<dim3(8, 128), 256, 0, stream>>>(x, W1, b1, h1, M_, H_, I_, I_);
    mgemm_bt<1, float><<<dim3(8, 128), 256, 0, stream>>>(h1, W2, b2, h2, M_, H_, H_, H_);
    mgemm_bt<0, __hip_bfloat16><<<dim3(24, 128), 256, 0, stream>>>(h2, Wih, bih, xg, M_, H3_, H_, H_);
    f32_to_bf16_k<<<768, 256, 0, stream>>>(Whh, Wbf, H3_ * H_);
    gru_init_k<<<32, 256, 0, stream>>>(hbuf, tags);
    gru_scan<__hip_bfloat16><<<GRU_NB, 256, 0, stream>>>(xg, Wbf, bhh, hs, H_, hbuf, tags);
    mgemm_bt<0, float><<<dim3(3, 128), 256, 0, stream>>>(hs, Wout, bout, out, M_, O_, H_, H_);
  }
  // else: insufficient workspace -> zeros (visible failure)
}

// Round 21
// 3733.509 us; speedup vs baseline: 3.8034x; 1.0101x over previous
//
#include <hip/hip_runtime.h>
#include <hip/hip_bf16.h>

#define B_  32
#define T_  512
#define I_  512
#define H_  1024
#define O_  360
#define H3_ 3072
#define M_  (B_*T_)      // 16384

static constexpr int GRU_NB = 64;   // scan blocks (16 units each)

typedef __bf16 bf16x8 __attribute__((ext_vector_type(8)));
typedef float  f32x4  __attribute__((ext_vector_type(4)));

__device__ __forceinline__ float sigmoidf_(float x) {
  return 1.0f / (1.0f + __expf(-x));
}
// fast tanh via expf: exact at saturation, ~1e-7 rel err midrange
__device__ __forceinline__ float tanhf_(float x) {
  float e = __expf(2.0f * x);
  return 1.0f - 2.0f / (e + 1.0f);
}
__device__ __forceinline__ float ld_f32(const float* p) { return *p; }
__device__ __forceinline__ float ld_f32(const __hip_bfloat16* p) { return __bfloat162float(*p); }
__device__ __forceinline__ void st_f32(float* p, float v) { *p = v; }
__device__ __forceinline__ void st_f32(__hip_bfloat16* p, float v) { *p = __float2bfloat16(v); }
__device__ __forceinline__ unsigned short bf16_bits(float f) {
  __hip_bfloat16 b = __float2bfloat16(f);
  return *reinterpret_cast<unsigned short*>(&b);
}
__device__ __forceinline__ unsigned short bits_of(__hip_bfloat16 b) {
  return *reinterpret_cast<unsigned short*>(&b);
}

// ---------------------------------------------------------------- utilities
__global__ void f32_to_bf16_k(const float* __restrict__ in,
                              __hip_bfloat16* __restrict__ out, int n) {
  int i = blockIdx.x * blockDim.x + threadIdx.x;
  int stride = gridDim.x * blockDim.x;
  for (; i < n; i += stride) out[i] = __float2bfloat16(in[i]);
}

// tags: sector per (block,bt) pair -> 128 sectors x 16 u32 = 8KB; kh tags
// adjacent words within the sector (single u64 poll load).
__global__ void gru_init_k(__hip_bfloat16* __restrict__ hbuf,
                           unsigned* __restrict__ tags) {
  const int tid0  = blockIdx.x * blockDim.x + threadIdx.x;
  const int stride = gridDim.x * blockDim.x;
  for (int i = tid0; i < 2 * B_ * H_; i += stride) hbuf[i] = __float2bfloat16(0.0f);
  if (tid0 < 4096) tags[tid0] = 0u;
}

// ---------------------------------------------------------------- MFMA GEMM
// (unchanged from R13 — verified) split-bf16: D = Ah*Wh + Ah*Wl + Al*Wh,
// packed ds_write_b128 staging.
template <int ACT, typename OT>
__global__ __launch_bounds__(256)
void mgemm_bt(const float* __restrict__ A, const float* __restrict__ W,
              const float* __restrict__ bias, OT* __restrict__ C,
              int M, int N, int K, int lda) {
  __shared__ __hip_bfloat16 Ah[128][40], Al[128][40];
  __shared__ __hip_bfloat16 Wh[128][40], Wl[128][40];
  const int tid  = threadIdx.x;
  const int lane = tid & 63;
  const int wv   = tid >> 6;
  const int bm   = blockIdx.y * 128;
  const int bn   = blockIdx.x * 128;
  const int msub = (wv & 1) * 64;
  const int nsub = (wv >> 1) * 64;
  const int fr   = lane & 15;
  const int fk   = lane >> 4;

  f32x4 acc[4][4];
#pragma unroll
  for (int i = 0; i < 4; ++i)
#pragma unroll
    for (int j = 0; j < 4; ++j) acc[i][j] = (f32x4){0.f, 0.f, 0.f, 0.f};

  const int sr = tid >> 1;
  const int sc = (tid & 1) * 16;
  const float* Ap = A + (size_t)(bm + sr) * lda + sc;
  const bool wok = (bn + sr) < N;
  const float* Wp = W + (size_t)(wok ? (bn + sr) : 0) * K + sc;

  for (int k0 = 0; k0 < K; k0 += 32) {
    float av[16], wvv[16];
#pragma unroll
    for (int j = 0; j < 4; ++j) {
      float4 t = *(const float4*)(Ap + k0 + j * 4);
      av[j*4+0] = t.x; av[j*4+1] = t.y; av[j*4+2] = t.z; av[j*4+3] = t.w;
      float4 u = wok ? *(const float4*)(Wp + k0 + j * 4)
                     : make_float4(0.f, 0.f, 0.f, 0.f);
      wvv[j*4+0] = u.x; wvv[j*4+1] = u.y; wvv[j*4+2] = u.z; wvv[j*4+3] = u.w;
    }

    unsigned pah[8], pal[8], pwh[8], pwl[8];
#pragma unroll
    for (int e = 0; e < 8; ++e) {
      __hip_bfloat16 a0 = __float2bfloat16(av[2*e]);
      __hip_bfloat16 a1 = __float2bfloat16(av[2*e+1]);
      pah[e] = (unsigned)bits_of(a0) | ((unsigned)bits_of(a1) << 16);
      pal[e] = (unsigned)bf16_bits(av[2*e]   - __bfloat162float(a0)) |
               ((unsigned)bf16_bits(av[2*e+1] - __bfloat162float(a1)) << 16);
      __hip_bfloat16 w0 = __float2bfloat16(wvv[2*e]);
      __hip_bfloat16 w1 = __float2bfloat16(wvv[2*e+1]);
      pwh[e] = (unsigned)bits_of(w0) | ((unsigned)bits_of(w1) << 16);
      pwl[e] = (unsigned)bf16_bits(wvv[2*e]   - __bfloat162float(w0)) |
               ((unsigned)bf16_bits(wvv[2*e+1] - __bfloat162float(w1)) << 16);
    }

    __syncthreads();
    *(uint4*)&Ah[sr][sc]     = make_uint4(pah[0], pah[1], pah[2], pah[3]);
    *(uint4*)&Ah[sr][sc + 8] = make_uint4(pah[4], pah[5], pah[6], pah[7]);
    *(uint4*)&Al[sr][sc]     = make_uint4(pal[0], pal[1], pal[2], pal[3]);
    *(uint4*)&Al[sr][sc + 8] = make_uint4(pal[4], pal[5], pal[6], pal[7]);
    *(uint4*)&Wh[sr][sc]     = make_uint4(pwh[0], pwh[1], pwh[2], pwh[3]);
    *(uint4*)&Wh[sr][sc + 8] = make_uint4(pwh[4], pwh[5], pwh[6], pwh[7]);
    *(uint4*)&Wl[sr][sc]     = make_uint4(pwl[0], pwl[1], pwl[2], pwl[3]);
    *(uint4*)&Wl[sr][sc + 8] = make_uint4(pwl[4], pwl[5], pwl[6], pwl[7]);
    __syncthreads();

    bf16x8 ah[4], al[4];
#pragma unroll
    for (int mf = 0; mf < 4; ++mf) {
      ah[mf] = *(const bf16x8*)&Ah[msub + mf * 16 + fr][fk * 8];
      al[mf] = *(const bf16x8*)&Al[msub + mf * 16 + fr][fk * 8];
    }
#pragma unroll
    for (int nf = 0; nf < 4; ++nf) {
      bf16x8 bh = *(const bf16x8*)&Wh[nsub + nf * 16 + fr][fk * 8];
      bf16x8 bl = *(const bf16x8*)&Wl[nsub + nf * 16 + fr][fk * 8];
#pragma unroll
      for (int mf = 0; mf < 4; ++mf) {
        acc[mf][nf] = __builtin_amdgcn_mfma_f32_16x16x32_bf16(ah[mf], bh, acc[mf][nf], 0, 0, 0);
        acc[mf][nf] = __builtin_amdgcn_mfma_f32_16x16x32_bf16(ah[mf], bl, acc[mf][nf], 0, 0, 0);
        acc[mf][nf] = __builtin_amdgcn_mfma_f32_16x16x32_bf16(al[mf], bh, acc[mf][nf], 0, 0, 0);
      }
    }
  }

#pragma unroll
  for (int nf = 0; nf < 4; ++nf) {
    const int n = bn + nsub + nf * 16 + fr;
    if (n < N) {
      const float bj = bias[n];
#pragma unroll
      for (int mf = 0; mf < 4; ++mf)
#pragma unroll
        for (int r = 0; r < 4; ++r) {
          const int m = bm + msub + mf * 16 + fk * 4 + r;
          float v = acc[mf][nf][r] + bj;
          if (ACT) v = fmaxf(v, 0.0f);
          st_f32(&C[(size_t)m * N + n], v);
        }
    }
  }
}

// ---------------------------------------------------------------- GRU scan
// R20 structure (K-split 4 waves = (bt,kh); gate-split; LDS-resident W_hh;
// padded L3 tags; no RMW; fast tanh) + poll trims:
//  (1) paired tags: (block,bt) sector holds kh0/kh1 tags in ADJACENT words
//      -> poll is ONE relaxed u64 load per block (was two u32 loads);
//      cross-block 64B padding retained.
//  (2) no s_sleep backoff: pure spin (padding already killed the tag-bank
//      contention; sleep only added detection lag).
// Lap-safety unchanged: tag(block,bt,kh)=t implies that wave's A-reads of
// h(t-1) and PS reads completed; consumers poll ALL same-bt (block,kh) tags.
// NOTE: xg and hs may ALIAS (fp32 path).
template <typename XT>
__global__ __launch_bounds__(256)
void gru_scan(const XT* xg,                            // [B,T,3H]
              const __hip_bfloat16* __restrict__ Wbf,  // [3H][H] bf16
              const float* __restrict__ bhh,           // [3H]
              float* hs, int hs_ld,                    // [B,T,*] out
              __hip_bfloat16* hbuf,                    // [2][B][H] bf16
              unsigned* tags) {                        // [128 sectors x 16 u32]
  __shared__ uint4 WL4[6144];      // 96 KiB: r,z,n gate slices, swizzled
  __shared__ float PS[128 * 13];   // partial exchange, stride 13
  const int tid  = threadIdx.x;
  const int lane = tid & 63;
  const int wv   = tid >> 6;
  const int bt   = wv & 1;         // batch half
  const int kh   = wv >> 1;        // K half (also owns c-rows 2kh..2kh+1)
  const int col  = lane & 15;
  const int krow = lane >> 4;
  const int u0   = blockIdx.x * 16;
  const int u    = u0 + col;
  const int bb   = bt * 16 + krow * 4;
  const int c7   = col & 7;
  const int cb   = kh * 2;         // this wave's first owned c-row

  // ---- one-time LDS fill: gate g, local row l, 16B chunk c; swizzled
  for (int idx = tid; idx < 6144; idx += 256) {
    const int g = idx >> 11;           // 0=r, 1=z, 2=n
    const int l = (idx >> 7) & 15;
    const int c = idx & 127;
    const uint4 src = *(const uint4*)(Wbf + ((size_t)(g * H_ + u0 + l)) * H_ + c * 8);
    WL4[g * 2048 + l * 128 + (c ^ (l & 7))] = src;
  }
  __syncthreads();

  const float bhr = bhh[u];
  const float bhz = bhh[H_ + u];
  const float bhn = bhh[2 * H_ + u];

  // tag layout: sector ((block<<1)|bt)*16; word +kh
  const unsigned long long* tpair =
      (const unsigned long long*)(tags + (((lane << 1) | bt) << 4));
  unsigned* ourtag = tags + ((((blockIdx.x << 1) | bt) << 4) + kh);

  float* psme = PS + (bt * 64 + lane) * 13;

  float hold[2] = {0.f, 0.f};

  float pxr[2], pxz[2], pxn[2];
#pragma unroll
  for (int c = 0; c < 2; ++c) {
    const XT* xp = xg + ((size_t)(bb + cb + c) * T_ + 0) * H3_;
    pxr[c] = ld_f32(xp + u);
    pxz[c] = ld_f32(xp + H_ + u);
    pxn[c] = ld_f32(xp + 2 * H_ + u);
  }

  for (int t = 0; t < T_; ++t) {
    const int cur = t & 1;

    // ---- wait: both kh tags of every same-bt block reached t (u64 spin)
    if (t > 0) {
      const unsigned want = (unsigned)t;
      for (;;) {
        const unsigned long long g =
            __hip_atomic_load(tpair, __ATOMIC_RELAXED, __HIP_MEMORY_SCOPE_AGENT);
        const unsigned g0 = (unsigned)g;
        const unsigned g1 = (unsigned)(g >> 32);
        if (!__any((g0 < want) || (g1 < want))) break;
      }
      __builtin_amdgcn_sched_barrier(0);
    }

    // opaque zero: blocks LICM from hoisting the invariant ds_reads
    int tz;
    asm volatile("v_mov_b32 %0, 0" : "=v"(tz));
    const uint4* WLp = WL4 + col * 128 + tz;

    // this wave's K-half: 16 chunks, single wait group
    const unsigned long long* ab =
        (const unsigned long long*)(hbuf + cur * (B_ * H_)) +
        (size_t)(bt * 16 + col) * 256 + kh * 128 + krow * 2;

    f32x4 ar = {0.f, 0.f, 0.f, 0.f};
    f32x4 az = {0.f, 0.f, 0.f, 0.f};
    f32x4 an = {0.f, 0.f, 0.f, 0.f};
#pragma unroll 16
    for (int ks = 0; ks < 16; ++ks) {
      union { unsigned long long q[2]; bf16x8 v; } A;
      A.q[0] = __hip_atomic_load(ab + ks * 8 + 0, __ATOMIC_RELAXED, __HIP_MEMORY_SCOPE_AGENT);
      A.q[1] = __hip_atomic_load(ab + ks * 8 + 1, __ATOMIC_RELAXED, __HIP_MEMORY_SCOPE_AGENT);
      const int cx = (krow + (kh * 16 + ks) * 4) ^ c7;
      bf16x8 wrv = __builtin_bit_cast(bf16x8, WLp[cx]);
      bf16x8 wzv = __builtin_bit_cast(bf16x8, WLp[2048 + cx]);
      bf16x8 wnv = __builtin_bit_cast(bf16x8, WLp[4096 + cx]);
      ar = __builtin_amdgcn_mfma_f32_16x16x32_bf16(A.v, wrv, ar, 0, 0, 0);
      az = __builtin_amdgcn_mfma_f32_16x16x32_bf16(A.v, wzv, az, 0, 0, 0);
      an = __builtin_amdgcn_mfma_f32_16x16x32_bf16(A.v, wnv, an, 0, 0, 0);
    }

    // ---- cross-exchange the partials for the OTHER wave's c-rows
    // kh=0 writes its c=2,3 at [0..5]; kh=1 writes its c=0,1 at [6..11]
    {
      const int co = 2 - cb;            // other wave's first c-row
      const int wbase = kh ? 6 : 0;
      psme[wbase + 0] = ar[co];     psme[wbase + 1] = az[co];
      psme[wbase + 2] = an[co];     psme[wbase + 3] = ar[co + 1];
      psme[wbase + 4] = az[co + 1]; psme[wbase + 5] = an[co + 1];
    }
    __syncthreads();

    // ---- reduce own c-rows, gates, publish, drain, own tag
    const int rbase = kh ? 0 : 6;
    float hv[2];
#pragma unroll
    for (int c = 0; c < 2; ++c) {
      const float sr_ = ar[cb + c] + psme[rbase + c * 3 + 0];
      const float sz_ = az[cb + c] + psme[rbase + c * 3 + 1];
      const float sn_ = an[cb + c] + psme[rbase + c * 3 + 2];
      const float r = sigmoidf_(pxr[c] + sr_ + bhr);
      const float z = sigmoidf_(pxz[c] + sz_ + bhz);
      const float n = tanhf_(pxn[c] + r * (sn_ + bhn));
      const float h = (1.0f - z) * n + z * hold[c];
      hold[c] = h;
      hv[c] = h;
    }

    // publish: even-col lanes store the (u,u+1) packed word for each row
    unsigned* hn32 = (unsigned*)(hbuf + (cur ^ 1) * (B_ * H_));
    const int ue2 = (u & ~1) >> 1;
#pragma unroll
    for (int c = 0; c < 2; ++c) {
      const float other = __shfl_xor(hv[c], 1, 64);
      if (!(lane & 1)) {
        const unsigned p = (unsigned)bf16_bits(hv[c]) |
                           ((unsigned)bf16_bits(other) << 16);
        __hip_atomic_store(hn32 + (size_t)(bb + cb + c) * 512 + ue2, p,
                           __ATOMIC_RELAXED, __HIP_MEMORY_SCOPE_AGENT);
      }
    }

    asm volatile("s_waitcnt vmcnt(0)" ::: "memory");
    if (lane == 0)
      __hip_atomic_store(ourtag, (unsigned)(t + 1),
                         __ATOMIC_RELAXED, __HIP_MEMORY_SCOPE_AGENT);

    // ---- off-critical-path: hs stores + xg(t+1) prefetch (own 2 rows)
#pragma unroll
    for (int c = 0; c < 2; ++c)
      hs[((size_t)(bb + cb + c) * T_ + t) * hs_ld + u] = hv[c];

    if (t + 1 < T_) {
#pragma unroll
      for (int c = 0; c < 2; ++c) {
        const XT* xp = xg + ((size_t)(bb + cb + c) * T_ + (t + 1)) * H3_;
        pxr[c] = ld_f32(xp + u);
        pxz[c] = ld_f32(xp + H_ + u);
        pxn[c] = ld_f32(xp + 2 * H_ + u);
      }
    }
  }
}

// ---------------------------------------------------------------- launch
extern "C" void kernel_launch(void* const* d_in, const int* in_sizes, int n_in,
                              void* d_out, int out_size, void* d_ws, size_t ws_size,
                              hipStream_t stream) {
  const float* x    = (const float*)d_in[0];
  const float* W1   = (const float*)d_in[1];
  const float* b1   = (const float*)d_in[2];
  const float* W2   = (const float*)d_in[3];
  const float* b2   = (const float*)d_in[4];
  const float* Wih  = (const float*)d_in[5];
  const float* bih  = (const float*)d_in[6];
  const float* Whh  = (const float*)d_in[7];
  const float* bhh  = (const float*)d_in[8];
  const float* Wout = (const float*)d_in[9];
  const float* bout = (const float*)d_in[10];
  float* out = (float*)d_out;

  const size_t MB = (size_t)1 << 20;
  char* ws = (char*)d_ws;

  if (ws_size >= 256 * MB) {
    // [0,64M): h2, later Wbf(6M)+hbuf(@8M)+tags(@9M, 16KB)
    // [64,256M): xg fp32; h1 aliased at start; hs interleaved in r columns.
    float* h2 = (float*)ws;
    float* h1 = (float*)(ws + 64 * MB);
    float* xg = (float*)(ws + 64 * MB);
    __hip_bfloat16* Wbf  = (__hip_bfloat16*)ws;
    __hip_bfloat16* hbuf = (__hip_bfloat16*)(ws + 8 * MB);
    unsigned* tags = (unsigned*)(ws + 9 * MB);
    float* hs = xg;  const int hs_ld = H3_;

    mgemm_bt<1, float><<<dim3(8, 128), 256, 0, stream>>>(x, W1, b1, h1, M_, H_, I_, I_);
    mgemm_bt<1, float><<<dim3(8, 128), 256, 0, stream>>>(h1, W2, b2, h2, M_, H_, H_, H_);
    mgemm_bt<0, float><<<dim3(24, 128), 256, 0, stream>>>(h2, Wih, bih, xg, M_, H3_, H_, H_);
    f32_to_bf16_k<<<768, 256, 0, stream>>>(Whh, Wbf, H3_ * H_);
    gru_init_k<<<32, 256, 0, stream>>>(hbuf, tags);
    gru_scan<float><<<GRU_NB, 256, 0, stream>>>(xg, Wbf, bhh, hs, hs_ld, hbuf, tags);
    mgemm_bt<0, float><<<dim3(3, 128), 256, 0, stream>>>(hs, Wout, bout, out, M_, O_, H_, hs_ld);
  } else if (ws_size >= 167 * MB) {
    float* h2 = (float*)ws;
    float* hs = (float*)ws;
    float* h1 = (float*)(ws + 64 * MB);
    __hip_bfloat16* xg   = (__hip_bfloat16*)(ws + 64 * MB);
    __hip_bfloat16* Wbf  = (__hip_bfloat16*)(ws + 160 * MB);
    __hip_bfloat16* hbuf = (__hip_bfloat16*)(ws + 166 * MB);
    unsigned* tags = (unsigned*)(ws + 166 * MB + 256 * 1024);

    mgemm_bt<1, float><<<dim3(8, 128), 256, 0, stream>>>(x, W1, b1, h1, M_, H_, I_, I_);
    mgemm_bt<1, float><<<dim3(8, 128), 256, 0, stream>>>(h1, W2, b2, h2, M_, H_, H_, H_);
    mgemm_bt<0, __hip_bfloat16><<<dim3(24, 128), 256, 0, stream>>>(h2, Wih, bih, xg, M_, H3_, H_, H_);
    f32_to_bf16_k<<<768, 256, 0, stream>>>(Whh, Wbf, H3_ * H_);
    gru_init_k<<<32, 256, 0, stream>>>(hbuf, tags);
    gru_scan<__hip_bfloat16><<<GRU_NB, 256, 0, stream>>>(xg, Wbf, bhh, hs, H_, hbuf, tags);
    mgemm_bt<0, float><<<dim3(3, 128), 256, 0, stream>>>(hs, Wout, bout, out, M_, O_, H_, H_);
  }
  // else: insufficient workspace -> zeros (visible failure)
}